// Round 4
// baseline (806.831 us; speedup 1.0000x reference)
//
#include <hip/hip_runtime.h>
#include <hip/hip_bf16.h>

#define N_NODES 50000
#define N_EDGES 500000
#define N_REL   50
#define NTILES  ((N_EDGES + 63) / 64)   // 7813
#define PBLOCKS 768
#define NODE_TILES ((N_NODES + 63) / 64)  // 782

// workspace layout (floats)
#define CNT_OFF 0
#define S1_OFF  (N_NODES)
#define S2_OFF  (S1_OFF + N_NODES*16)
#define ZERO_FLOATS (S2_OFF + N_NODES*64)
#define H1_OFF  ZERO_FLOATS                 // h1 stored as bf16 (short*) in this slot
#define H2_OFF  (H1_OFF + N_NODES*64)       // h2 stored as bf16 (short*) in this slot

typedef short short8  __attribute__((ext_vector_type(8)));
typedef short short4v __attribute__((ext_vector_type(4)));
typedef float f32x4   __attribute__((ext_vector_type(4)));
typedef float f4      __attribute__((ext_vector_type(4)));

#define MFMA16(a,b,c) __builtin_amdgcn_mfma_f32_16x16x32_bf16((a),(b),(c),0,0,0)

__device__ __forceinline__ short f2bf(float x) {
    unsigned u = __float_as_uint(x);
    unsigned r = (u + 0x7fffu + ((u >> 16) & 1u)) >> 16;   // RNE
    return (short)r;
}
__device__ __forceinline__ float bf2f(short s) {
    return __uint_as_float(((unsigned)(unsigned short)s) << 16);
}

__device__ __forceinline__ short8 load_wfrag(const float* __restrict__ W, int row, int K, int k) {
    const f4* p = (const f4*)(W + (size_t)row * K + k);
    f4 a = p[0], b = p[1];
    short8 r;
    r[0] = f2bf(a[0]); r[1] = f2bf(a[1]); r[2] = f2bf(a[2]); r[3] = f2bf(a[3]);
    r[4] = f2bf(b[0]); r[5] = f2bf(b[1]); r[6] = f2bf(b[2]); r[7] = f2bf(b[3]);
    return r;
}

__device__ __forceinline__ void gload_lds16(const void* g, void* l) {
    __builtin_amdgcn_global_load_lds(
        (const __attribute__((address_space(1))) void*)g,
        (__attribute__((address_space(3))) void*)l, 16, 0, 0);
}

// ---------------- scatter kernels ----------------

__global__ __launch_bounds__(256) void k_scatter1(
    const float* __restrict__ x, const int* __restrict__ src,
    const int* __restrict__ dst, float* __restrict__ s1, float* __restrict__ cnt)
{
    int t = blockIdx.x * blockDim.x + threadIdx.x;
    if (t >= N_EDGES * 16) return;
    int e = t >> 4, f = t & 15;
    int s = src[e], d = dst[e];
    atomicAdd(&s1[d * 16 + f], x[s * 16 + f]);
    if (f == 0) atomicAdd(&cnt[d], 1.0f);
}

// h1 is bf16 now: read short4, convert, f32-atomic into s2
__global__ __launch_bounds__(256) void k_scatter2(
    const short* __restrict__ h1b, const int* __restrict__ src,
    const int* __restrict__ dst, float* __restrict__ s2)
{
    int t = blockIdx.x * blockDim.x + threadIdx.x;
    if (t >= N_EDGES * 16) return;
    int e = t >> 4, q = t & 15;
    int s = src[e], d = dst[e];
    short4v v = *(const short4v*)&h1b[(size_t)s * 64 + q * 4];
    float* p = &s2[(size_t)d * 64 + q * 4];
#pragma unroll
    for (int j = 0; j < 4; ++j) atomicAdd(p + j, bf2f(v[j]));
}

// ---------------- SAGE1 via MFMA: K=32 (mean||x) -> 64 outs, h1 out bf16 ----
__global__ __launch_bounds__(256) void k_sage1_mfma(
    const float* __restrict__ x, const float* __restrict__ s1,
    const float* __restrict__ cnt,
    const float* __restrict__ w1_l, const float* __restrict__ b1,
    const float* __restrict__ w1_r, short* __restrict__ h1b)
{
    __shared__ short feat[64 * 40];

    const int t    = threadIdx.x;
    const int w    = t >> 6;
    const int lane = t & 63;
    const int lr   = lane & 15;
    const int lg   = lane >> 4;
    const int base = blockIdx.x * 64;

    short8 w1f;
    if (lg < 2) w1f = load_wfrag(w1_l, w * 16 + lr, 16, lg * 8);
    else        w1f = load_wfrag(w1_r, w * 16 + lr, 16, (lg - 2) * 8);

    {
        int e  = t >> 2, q = t & 3;
        int ng = base + e;
        short8 v = (short8)0;
        if (ng < N_NODES) {
            if (q < 2) {
                float c = cnt[ng];
                c = c < 1.0f ? 1.0f : c;
                float inv = 1.0f / c;
                f4 a = *(const f4*)(s1 + (size_t)ng * 16 + q * 8);
                f4 b = *(const f4*)(s1 + (size_t)ng * 16 + q * 8 + 4);
#pragma unroll
                for (int j = 0; j < 4; ++j) { v[j] = f2bf(a[j] * inv); v[4 + j] = f2bf(b[j] * inv); }
            } else {
                f4 a = *(const f4*)(x + (size_t)ng * 16 + (q - 2) * 8);
                f4 b = *(const f4*)(x + (size_t)ng * 16 + (q - 2) * 8 + 4);
#pragma unroll
                for (int j = 0; j < 4; ++j) { v[j] = f2bf(a[j]); v[4 + j] = f2bf(b[j]); }
            }
        }
        *(short8*)&feat[e * 40 + q * 8] = v;
    }
    __syncthreads();

    f32x4 acc[4];
    f4 bia = *(const f4*)&b1[w * 16 + lg * 4];
#pragma unroll
    for (int nt = 0; nt < 4; ++nt) {
        acc[nt][0] = bia[0]; acc[nt][1] = bia[1]; acc[nt][2] = bia[2]; acc[nt][3] = bia[3];
    }
#pragma unroll
    for (int nt = 0; nt < 4; ++nt) {
        int e = nt * 16 + lr;
        short8 bf = *(const short8*)&feat[e * 40 + lg * 8];
        acc[nt] = MFMA16(w1f, bf, acc[nt]);
    }
#pragma unroll
    for (int nt = 0; nt < 4; ++nt) {
        int ng = base + nt * 16 + lr;
        if (ng < N_NODES) {
            short4v o;
#pragma unroll
            for (int r = 0; r < 4; ++r) { float v = acc[nt][r]; o[r] = f2bf(v > 0.0f ? v : 0.0f); }
            *(short4v*)&h1b[(size_t)ng * 64 + w * 16 + lg * 4] = o;
        }
    }
}

// ---------------- SAGE2 via MFMA: K=128 (h1||mean) -> 128 outs, h2 out bf16 --
__global__ __launch_bounds__(256) void k_sage2_mfma(
    const short* __restrict__ h1b, const float* __restrict__ s2,
    const float* __restrict__ cnt,
    const float* __restrict__ w2_l, const float* __restrict__ b2,
    const float* __restrict__ w2_r, short* __restrict__ h2b)
{
    __shared__ short feat[64 * 128];

    const int t    = threadIdx.x;
    const int w    = t >> 6;
    const int lane = t & 63;
    const int lr   = lane & 15;
    const int lg   = lane >> 4;
    const int base = blockIdx.x * 64;

    short8 wf[2][4];
#pragma unroll
    for (int mt = 0; mt < 2; ++mt)
#pragma unroll
        for (int kt = 0; kt < 4; ++kt) {
            int row = w * 32 + mt * 16 + lr;
            int k   = kt * 32 + lg * 8;
            wf[mt][kt] = (k < 64) ? load_wfrag(w2_r, row, 64, k)
                                  : load_wfrag(w2_l, row, 64, k - 64);
        }

    {
        int e  = t >> 2, q = t & 3;
        int ng = base + e;
        if (q < 2) {
            const short* hp = (ng < N_NODES) ? (h1b + (size_t)ng * 64 + q * 32) : nullptr;
#pragma unroll
            for (int j = 0; j < 4; ++j) {
                short8 v = hp ? *(const short8*)(hp + j * 8) : (short8)0;
                int cc   = q * 4 + j;
                int scol = (cc * 8) ^ ((e & 7) << 3);
                *(short8*)&feat[e * 128 + scol] = v;
            }
        } else {
            float inv = 1.0f;
            const float* srcp = nullptr;
            if (ng < N_NODES) {
                float c = cnt[ng];
                c = c < 1.0f ? 1.0f : c;
                inv = 1.0f / c;
                srcp = s2 + (size_t)ng * 64 + (q - 2) * 32;
            }
#pragma unroll
            for (int j = 0; j < 4; ++j) {
                short8 v = (short8)0;
                if (srcp) {
                    f4 a = *(const f4*)(srcp + j * 8);
                    f4 b = *(const f4*)(srcp + j * 8 + 4);
#pragma unroll
                    for (int q2 = 0; q2 < 4; ++q2) { v[q2] = f2bf(a[q2] * inv); v[4 + q2] = f2bf(b[q2] * inv); }
                }
                int cc   = q * 4 + j;
                int scol = (cc * 8) ^ ((e & 7) << 3);
                *(short8*)&feat[e * 128 + scol] = v;
            }
        }
    }
    __syncthreads();

    f32x4 acc[2][4];
#pragma unroll
    for (int mt = 0; mt < 2; ++mt) {
        f4 bia = *(const f4*)&b2[w * 32 + mt * 16 + lg * 4];
#pragma unroll
        for (int nt = 0; nt < 4; ++nt) {
            acc[mt][nt][0] = bia[0]; acc[mt][nt][1] = bia[1];
            acc[mt][nt][2] = bia[2]; acc[mt][nt][3] = bia[3];
        }
    }
#pragma unroll
    for (int kt = 0; kt < 4; ++kt) {
        short8 bf[4];
#pragma unroll
        for (int nt = 0; nt < 4; ++nt) {
            int e = nt * 16 + lr;
            int k = kt * 32 + lg * 8;
            int scol = k ^ ((e & 7) << 3);
            bf[nt] = *(const short8*)&feat[e * 128 + scol];
        }
#pragma unroll
        for (int mt = 0; mt < 2; ++mt)
#pragma unroll
            for (int nt = 0; nt < 4; ++nt)
                acc[mt][nt] = MFMA16(wf[mt][kt], bf[nt], acc[mt][nt]);
    }
#pragma unroll
    for (int mt = 0; mt < 2; ++mt)
#pragma unroll
        for (int nt = 0; nt < 4; ++nt) {
            int ng = base + nt * 16 + lr;
            if (ng < N_NODES) {
                short4v o;
#pragma unroll
                for (int r = 0; r < 4; ++r) { float v = acc[mt][nt][r]; o[r] = f2bf(v > 0.0f ? v : 0.0f); }
                *(short4v*)&h2b[(size_t)ng * 128 + w * 32 + mt * 16 + lg * 4] = o;
            }
        }
}

// ---------------- fused edge MLP ----------------
// feat staged via global_load_lds: LDS linear, swizzle carried by the per-lane
// GLOBAL source chunk index u = p ^ (e&7)  (LDS position p holds chunk u, so
// reads at scol = k ^ ((e&7)<<3) retrieve chunk k -- same layout as before).
// Tail (L3/L4/rf1/rf2/rf3) is wave-local: wave w owns edges [w*16, w*16+16),
// scratch aliased into act1 (dead after L2), wave-synchronous LDS (no barrier;
// same-wave ds write->read ordering is guaranteed, precedent: act3 path).
__global__ __launch_bounds__(256, 3) void k_edge_fused(
    const short* __restrict__ h2b, const int* __restrict__ src,
    const int* __restrict__ dst, const int* __restrict__ y,
    const float* __restrict__ ow1, const float* __restrict__ ob1,
    const float* __restrict__ ow2, const float* __restrict__ ob2,
    const float* __restrict__ ow3, const float* __restrict__ ob3,
    const float* __restrict__ ow4, const float* __restrict__ ob4,
    const float* __restrict__ rw1, const float* __restrict__ rb1,
    const float* __restrict__ rw2, const float* __restrict__ rb2,
    const float* __restrict__ rw3, const float* __restrict__ rb3,
    float* __restrict__ out)
{
    __shared__ short feat[64 * 256];   // 32KB; act2/act3 alias after L1
    __shared__ short act1[64 * 128];   // 16KB; tail scratch aliases after L2
    __shared__ float sw[662];

    short* act2 = feat;                // 64*64 shorts
    short* act3 = feat + 64 * 64;      // 64*32 shorts
    float* tailf = (float*)act1;       // 4096 floats; wave w uses [w*512, w*512+512)

    const int t    = threadIdx.x;
    const int w    = t >> 6;
    const int lane = t & 63;
    const int lr   = lane & 15;
    const int lg   = lane >> 4;

    if (t < 128) sw[t]       = ob1[t];
    if (t < 64)  sw[128 + t] = ob2[t];
    if (t < 32)  sw[192 + t] = ob3[t];
    if (t < 16)  sw[224 + t] = ob4[t];
    if (t < 8)   sw[240 + t] = rb1[t];
    if (t < 4)   sw[248 + t] = rb2[t];
    if (t < 50)  sw[252 + t] = rb3[t];
    if (t < 128) sw[302 + t] = rw1[t];
    if (t < 32)  sw[430 + t] = rw2[t];
    if (t < 200) sw[462 + t] = rw3[t];

    short8 w1f[2][8];
#pragma unroll
    for (int mt = 0; mt < 2; ++mt)
#pragma unroll
        for (int kt = 0; kt < 8; ++kt)
            w1f[mt][kt] = load_wfrag(ow1, w * 32 + mt * 16 + lr, 256, kt * 32 + lg * 8);

    short8 w2f[4];
#pragma unroll
    for (int kt = 0; kt < 4; ++kt)
        w2f[kt] = load_wfrag(ow2, w * 16 + lr, 128, kt * 32 + lg * 8);

    short8 w3f[2][2];
#pragma unroll
    for (int mt = 0; mt < 2; ++mt)
#pragma unroll
        for (int kt = 0; kt < 2; ++kt)
            w3f[mt][kt] = load_wfrag(ow3, mt * 16 + lr, 64, kt * 32 + lg * 8);

    short8 w4f = load_wfrag(ow4, lr, 32, lg * 8);

    for (int tile = blockIdx.x; tile < NTILES; tile += PBLOCKS) {
        const int base = tile * 64;

        // ---- stage feat via global_load_lds (8 issues/wave; 2 rows each) ----
#pragma unroll
        for (int i = 0; i < 8; ++i) {
            int r0 = w * 16 + i * 2;
            int e  = r0 + (lane >> 5);
            int p  = lane & 31;
            int u  = p ^ (e & 7);               // global chunk to fetch
            int eg = base + e;
            int ec = eg < N_EDGES ? eg : 0;     // clamp (outputs gated later)
            const int* ids = (u < 16) ? src : dst;
            int node = ids[ec];
            const short* g = h2b + (size_t)node * 128 + (u & 15) * 8;
            gload_lds16(g, &feat[r0 * 256]);
        }
        __syncthreads();

        // ---- L1: 256 -> 128, relu ----
        {
            f32x4 acc[2][4];
#pragma unroll
            for (int mt = 0; mt < 2; ++mt) {
                f32x4 bia;
#pragma unroll
                for (int r = 0; r < 4; ++r) bia[r] = sw[w * 32 + mt * 16 + lg * 4 + r];
#pragma unroll
                for (int nt = 0; nt < 4; ++nt) acc[mt][nt] = bia;
            }
#pragma unroll
            for (int kt = 0; kt < 8; ++kt) {
                short8 bf[4];
#pragma unroll
                for (int nt = 0; nt < 4; ++nt) {
                    int e = nt * 16 + lr;
                    int k = kt * 32 + lg * 8;
                    int scol = k ^ ((e & 7) << 3);
                    bf[nt] = *(const short8*)&feat[e * 256 + scol];
                }
#pragma unroll
                for (int mt = 0; mt < 2; ++mt)
#pragma unroll
                    for (int nt = 0; nt < 4; ++nt)
                        acc[mt][nt] = MFMA16(w1f[mt][kt], bf[nt], acc[mt][nt]);
            }
#pragma unroll
            for (int mt = 0; mt < 2; ++mt)
#pragma unroll
                for (int nt = 0; nt < 4; ++nt) {
                    int e  = nt * 16 + lr;
                    int n0 = w * 32 + mt * 16 + lg * 4;
                    short4v s;
#pragma unroll
                    for (int r = 0; r < 4; ++r) {
                        float v = acc[mt][nt][r];
                        s[r] = f2bf(v > 0.0f ? v : 0.0f);
                    }
                    int scol = n0 ^ ((e & 7) << 3);
                    *(short4v*)&act1[e * 128 + scol] = s;
                }
        }
        __syncthreads();

        // ---- L2: 128 -> 64, relu ----
        {
            f32x4 acc[4];
            f32x4 bia;
#pragma unroll
            for (int r = 0; r < 4; ++r) bia[r] = sw[128 + w * 16 + lg * 4 + r];
#pragma unroll
            for (int nt = 0; nt < 4; ++nt) acc[nt] = bia;
#pragma unroll
            for (int kt = 0; kt < 4; ++kt) {
#pragma unroll
                for (int nt = 0; nt < 4; ++nt) {
                    int e = nt * 16 + lr;
                    int k = kt * 32 + lg * 8;
                    int scol = k ^ ((e & 7) << 3);
                    short8 bf = *(const short8*)&act1[e * 128 + scol];
                    acc[nt] = MFMA16(w2f[kt], bf, acc[nt]);
                }
            }
#pragma unroll
            for (int nt = 0; nt < 4; ++nt) {
                int e  = nt * 16 + lr;
                int n0 = w * 16 + lg * 4;
                short4v s;
#pragma unroll
                for (int r = 0; r < 4; ++r) {
                    float v = acc[nt][r];
                    s[r] = f2bf(v > 0.0f ? v : 0.0f);
                }
                int scol = n0 ^ ((e & 7) << 3);
                *(short4v*)&act2[e * 64 + scol] = s;
            }
        }
        __syncthreads();

        // ---- wave-local tail: L3, L4, rf1, rf2, rf3, y ----
        {
            const int e3 = w * 16 + lr;
            float* T = tailf + w * 512;    // A4:[16][17]=272 | A8:272+[16][9]=144 | A44:416+[16][5]=80

            // L3: 64 -> 32, relu
            f32x4 acc[2];
#pragma unroll
            for (int mt = 0; mt < 2; ++mt)
#pragma unroll
                for (int r = 0; r < 4; ++r) acc[mt][r] = sw[192 + mt * 16 + lg * 4 + r];
#pragma unroll
            for (int kt = 0; kt < 2; ++kt) {
                int k = kt * 32 + lg * 8;
                int scol = k ^ ((e3 & 7) << 3);
                short8 bf = *(const short8*)&act2[e3 * 64 + scol];
#pragma unroll
                for (int mt = 0; mt < 2; ++mt)
                    acc[mt] = MFMA16(w3f[mt][kt], bf, acc[mt]);
            }
#pragma unroll
            for (int mt = 0; mt < 2; ++mt) {
                short4v s;
#pragma unroll
                for (int r = 0; r < 4; ++r) {
                    float v = acc[mt][r];
                    s[r] = f2bf(v > 0.0f ? v : 0.0f);
                }
                *(short4v*)&act3[e3 * 32 + mt * 16 + lg * 4] = s;
            }
            __builtin_amdgcn_wave_barrier();

            // L4: 32 -> 16, NO relu
            {
                short8 bf = *(const short8*)&act3[e3 * 32 + lg * 8];
                f32x4 a4;
#pragma unroll
                for (int r = 0; r < 4; ++r) a4[r] = sw[224 + lg * 4 + r];
                a4 = MFMA16(w4f, bf, a4);
#pragma unroll
                for (int r = 0; r < 4; ++r) T[lr * 17 + lg * 4 + r] = a4[r];
            }
            __builtin_amdgcn_wave_barrier();

            // rf1: 16 -> 8, relu; lane (lg,lr): edge lr, outs {2lg, 2lg+1}
            {
                float af[16];
#pragma unroll
                for (int f = 0; f < 16; ++f) af[f] = T[lr * 17 + f];
#pragma unroll
                for (int oo = 0; oo < 2; ++oo) {
                    int o = lg * 2 + oo;
                    float v = sw[240 + o];
#pragma unroll
                    for (int f = 0; f < 16; ++f) v += af[f] * sw[302 + o * 16 + f];
                    T[272 + lr * 9 + o] = v > 0.0f ? v : 0.0f;
                }
            }
            __builtin_amdgcn_wave_barrier();

            // rf2: 8 -> 4, relu; lane (lg,lr): edge lr, out lg
            {
                float v = sw[248 + lg];
#pragma unroll
                for (int f = 0; f < 8; ++f) v += T[272 + lr * 9 + f] * sw[430 + lg * 8 + f];
                T[416 + lr * 5 + lg] = v > 0.0f ? v : 0.0f;
            }
            __builtin_amdgcn_wave_barrier();

            // y copy (lanes 0..15)
            if (lane < 16) {
                int eg = base + w * 16 + lane;
                if (eg < N_EDGES) out[(size_t)N_EDGES * N_REL + eg] = (float)y[eg];
            }

            // rf3: 4 -> 50; wave writes 16*50 contiguous floats
            size_t obase = (size_t)(base + w * 16) * N_REL;
#pragma unroll
            for (int k2 = 0; k2 < 13; ++k2) {
                int idx = k2 * 64 + lane;
                if (idx < 16 * N_REL) {
                    int el = idx / N_REL;
                    int o  = idx - el * N_REL;
                    if (base + w * 16 + el < N_EDGES) {
                        float v = sw[252 + o];
#pragma unroll
                        for (int f = 0; f < 4; ++f) v += T[416 + el * 5 + f] * sw[462 + o * 4 + f];
                        out[obase + idx] = v;
                    }
                }
            }
        }
        __syncthreads();   // protect feat (act2/act3) + act1 (tail T) from next tile
    }
}

extern "C" void kernel_launch(void* const* d_in, const int* in_sizes, int n_in,
                              void* d_out, int out_size, void* d_ws, size_t ws_size,
                              hipStream_t stream) {
    const float* x    = (const float*)d_in[0];
    const int*   ei   = (const int*)d_in[1];
    const int*   src  = ei;
    const int*   dst  = ei + N_EDGES;
    const int*   y    = (const int*)d_in[2];
    const float* w1_l = (const float*)d_in[3];
    const float* b1   = (const float*)d_in[4];
    const float* w1_r = (const float*)d_in[5];
    const float* w2_l = (const float*)d_in[6];
    const float* b2   = (const float*)d_in[7];
    const float* w2_r = (const float*)d_in[8];
    const float* ow1  = (const float*)d_in[9];
    const float* ob1  = (const float*)d_in[10];
    const float* ow2  = (const float*)d_in[11];
    const float* ob2  = (const float*)d_in[12];
    const float* ow3  = (const float*)d_in[13];
    const float* ob3  = (const float*)d_in[14];
    const float* ow4  = (const float*)d_in[15];
    const float* ob4  = (const float*)d_in[16];
    const float* rw1  = (const float*)d_in[17];
    const float* rb1  = (const float*)d_in[18];
    const float* rw2  = (const float*)d_in[19];
    const float* rb2  = (const float*)d_in[20];
    const float* rw3  = (const float*)d_in[21];
    const float* rb3  = (const float*)d_in[22];

    float* ws  = (float*)d_ws;
    float* cnt = ws + CNT_OFF;
    float* s1  = ws + S1_OFF;
    float* s2  = ws + S2_OFF;
    short* h1b = (short*)(ws + H1_OFF);
    short* h2b = (short*)(ws + H2_OFF);
    float* out = (float*)d_out;

    hipMemsetAsync(d_ws, 0, (size_t)ZERO_FLOATS * sizeof(float), stream);

    {
        int total = N_EDGES * 16;
        k_scatter1<<<(total + 255) / 256, 256, 0, stream>>>(x, src, dst, s1, cnt);
    }
    k_sage1_mfma<<<NODE_TILES, 256, 0, stream>>>(x, s1, cnt, w1_l, b1, w1_r, h1b);
    {
        int total = N_EDGES * 16;
        k_scatter2<<<(total + 255) / 256, 256, 0, stream>>>(h1b, src, dst, s2);
    }
    k_sage2_mfma<<<NODE_TILES, 256, 0, stream>>>(h1b, s2, cnt, w2_l, b2, w2_r, h2b);

    k_edge_fused<<<PBLOCKS, 256, 0, stream>>>(
        h2b, src, dst, y,
        ow1, ob1, ow2, ob2, ow3, ob3, ow4, ob4,
        rw1, rb1, rw2, rb2, rw3, rb3, out);
}

// Round 5
// 565.434 us; speedup vs baseline: 1.4269x; 1.4269x over previous
//
#include <hip/hip_runtime.h>
#include <hip/hip_bf16.h>

#define N_NODES 50000
#define N_EDGES 500000
#define N_REL   50
#define NTILES  ((N_EDGES + 63) / 64)   // 7813
#define PBLOCKS 768
#define NODE_TILES ((N_NODES + 63) / 64)  // 782

// workspace layout (float-sized slots)
#define CNTI_OFF   0                          // int[50000]  (memset to 0)
#define STARTS_OFF (CNTI_OFF + N_NODES)       // int[50000]
#define CURSOR_OFF (STARTS_OFF + N_NODES)     // int[50000]
#define EBUF_OFF   (CURSOR_OFF + N_NODES)     // int[500000] (src grouped by dst)
#define S1_OFF     (EBUF_OFF + N_EDGES)       // float[50000*16]
#define S2_OFF     (S1_OFF + N_NODES*16)      // float[50000*64]
#define H1_OFF     (S2_OFF + N_NODES*64)      // short[50000*64]  (bf16)
#define H2_OFF     (H1_OFF + N_NODES*32)      // short[50000*128] (bf16)
// end = H2_OFF + N_NODES*64 floats = 9.45M floats = 37.8 MB

typedef short short8  __attribute__((ext_vector_type(8)));
typedef short short4v __attribute__((ext_vector_type(4)));
typedef float f32x4   __attribute__((ext_vector_type(4)));
typedef float f4      __attribute__((ext_vector_type(4)));

#define MFMA16(a,b,c) __builtin_amdgcn_mfma_f32_16x16x32_bf16((a),(b),(c),0,0,0)

__device__ __forceinline__ short f2bf(float x) {
    unsigned u = __float_as_uint(x);
    unsigned r = (u + 0x7fffu + ((u >> 16) & 1u)) >> 16;   // RNE
    return (short)r;
}
__device__ __forceinline__ float bf2f(short s) {
    return __uint_as_float(((unsigned)(unsigned short)s) << 16);
}

__device__ __forceinline__ short8 load_wfrag(const float* __restrict__ W, int row, int K, int k) {
    const f4* p = (const f4*)(W + (size_t)row * K + k);
    f4 a = p[0], b = p[1];
    short8 r;
    r[0] = f2bf(a[0]); r[1] = f2bf(a[1]); r[2] = f2bf(a[2]); r[3] = f2bf(a[3]);
    r[4] = f2bf(b[0]); r[5] = f2bf(b[1]); r[6] = f2bf(b[2]); r[7] = f2bf(b[3]);
    return r;
}

__device__ __forceinline__ void gload_lds16(const void* g, void* l) {
    __builtin_amdgcn_global_load_lds(
        (const __attribute__((address_space(1))) void*)g,
        (__attribute__((address_space(3))) void*)l, 16, 0, 0);
}

// ---------------- CSR build: hist -> scan -> bucket ----------------

__global__ __launch_bounds__(256) void k_hist(
    const int* __restrict__ dst, int* __restrict__ cnt_i)
{
    int e = blockIdx.x * blockDim.x + threadIdx.x;
    if (e < N_EDGES) atomicAdd(&cnt_i[dst[e]], 1);
}

__global__ __launch_bounds__(1024) void k_scan(
    const int* __restrict__ cnt_i, int* __restrict__ starts, int* __restrict__ cursor)
{
    __shared__ int part[1024];
    const int i  = threadIdx.x;
    const int lo = i * 49;
    const int hi = min(N_NODES, lo + 49);
    int s = 0;
    for (int j = lo; j < hi; ++j) s += cnt_i[j];
    part[i] = s;
    __syncthreads();
    for (int d = 1; d < 1024; d <<= 1) {
        int v = (i >= d) ? part[i - d] : 0;
        __syncthreads();
        part[i] += v;
        __syncthreads();
    }
    int off = (i == 0) ? 0 : part[i - 1];
    for (int j = lo; j < hi; ++j) {
        starts[j] = off;
        cursor[j] = off;
        off += cnt_i[j];
    }
}

__global__ __launch_bounds__(256) void k_bucket(
    const int* __restrict__ src, const int* __restrict__ dst,
    int* __restrict__ cursor, int* __restrict__ ebuf)
{
    int e = blockIdx.x * blockDim.x + threadIdx.x;
    if (e < N_EDGES) {
        int pos = atomicAdd(&cursor[dst[e]], 1);
        ebuf[pos] = src[e];
    }
}

// ---------------- gather aggregation (replaces atomic scatter) ----------------

__global__ __launch_bounds__(256) void k_agg1(
    const float* __restrict__ x, const int* __restrict__ ebuf,
    const int* __restrict__ starts, const int* __restrict__ cnt_i,
    float* __restrict__ s1)
{
    int t = blockIdx.x * blockDim.x + threadIdx.x;
    if (t >= N_NODES * 16) return;
    int n = t >> 4, f = t & 15;
    int st = starts[n], c = cnt_i[n];
    float s = 0.0f;
    for (int i = 0; i < c; ++i) s += x[(size_t)ebuf[st + i] * 16 + f];
    s1[t] = s;
}

__global__ __launch_bounds__(256) void k_agg2(
    const short* __restrict__ h1b, const int* __restrict__ ebuf,
    const int* __restrict__ starts, const int* __restrict__ cnt_i,
    float* __restrict__ s2)
{
    int t = blockIdx.x * blockDim.x + threadIdx.x;
    if (t >= N_NODES * 64) return;
    int n = t >> 6, f = t & 63;
    int st = starts[n], c = cnt_i[n];
    float s = 0.0f;
    for (int i = 0; i < c; ++i) s += bf2f(h1b[(size_t)ebuf[st + i] * 64 + f]);
    s2[t] = s;
}

// ---------------- SAGE1 via MFMA: K=32 (mean||x) -> 64 outs, h1 out bf16 ----
__global__ __launch_bounds__(256) void k_sage1_mfma(
    const float* __restrict__ x, const float* __restrict__ s1,
    const int* __restrict__ cnt_i,
    const float* __restrict__ w1_l, const float* __restrict__ b1,
    const float* __restrict__ w1_r, short* __restrict__ h1b)
{
    __shared__ short feat[64 * 40];

    const int t    = threadIdx.x;
    const int w    = t >> 6;
    const int lane = t & 63;
    const int lr   = lane & 15;
    const int lg   = lane >> 4;
    const int base = blockIdx.x * 64;

    short8 w1f;
    if (lg < 2) w1f = load_wfrag(w1_l, w * 16 + lr, 16, lg * 8);
    else        w1f = load_wfrag(w1_r, w * 16 + lr, 16, (lg - 2) * 8);

    {
        int e  = t >> 2, q = t & 3;
        int ng = base + e;
        short8 v = (short8)0;
        if (ng < N_NODES) {
            if (q < 2) {
                int ci = cnt_i[ng];
                float inv = 1.0f / (float)(ci > 0 ? ci : 1);
                f4 a = *(const f4*)(s1 + (size_t)ng * 16 + q * 8);
                f4 b = *(const f4*)(s1 + (size_t)ng * 16 + q * 8 + 4);
#pragma unroll
                for (int j = 0; j < 4; ++j) { v[j] = f2bf(a[j] * inv); v[4 + j] = f2bf(b[j] * inv); }
            } else {
                f4 a = *(const f4*)(x + (size_t)ng * 16 + (q - 2) * 8);
                f4 b = *(const f4*)(x + (size_t)ng * 16 + (q - 2) * 8 + 4);
#pragma unroll
                for (int j = 0; j < 4; ++j) { v[j] = f2bf(a[j]); v[4 + j] = f2bf(b[j]); }
            }
        }
        *(short8*)&feat[e * 40 + q * 8] = v;
    }
    __syncthreads();

    f32x4 acc[4];
    f4 bia = *(const f4*)&b1[w * 16 + lg * 4];
#pragma unroll
    for (int nt = 0; nt < 4; ++nt) {
        acc[nt][0] = bia[0]; acc[nt][1] = bia[1]; acc[nt][2] = bia[2]; acc[nt][3] = bia[3];
    }
#pragma unroll
    for (int nt = 0; nt < 4; ++nt) {
        int e = nt * 16 + lr;
        short8 bf = *(const short8*)&feat[e * 40 + lg * 8];
        acc[nt] = MFMA16(w1f, bf, acc[nt]);
    }
#pragma unroll
    for (int nt = 0; nt < 4; ++nt) {
        int ng = base + nt * 16 + lr;
        if (ng < N_NODES) {
            short4v o;
#pragma unroll
            for (int r = 0; r < 4; ++r) { float v = acc[nt][r]; o[r] = f2bf(v > 0.0f ? v : 0.0f); }
            *(short4v*)&h1b[(size_t)ng * 64 + w * 16 + lg * 4] = o;
        }
    }
}

// ---------------- SAGE2 via MFMA: K=128 (h1||mean) -> 128 outs, h2 out bf16 --
__global__ __launch_bounds__(256) void k_sage2_mfma(
    const short* __restrict__ h1b, const float* __restrict__ s2,
    const int* __restrict__ cnt_i,
    const float* __restrict__ w2_l, const float* __restrict__ b2,
    const float* __restrict__ w2_r, short* __restrict__ h2b)
{
    __shared__ short feat[64 * 128];

    const int t    = threadIdx.x;
    const int w    = t >> 6;
    const int lane = t & 63;
    const int lr   = lane & 15;
    const int lg   = lane >> 4;
    const int base = blockIdx.x * 64;

    short8 wf[2][4];
#pragma unroll
    for (int mt = 0; mt < 2; ++mt)
#pragma unroll
        for (int kt = 0; kt < 4; ++kt) {
            int row = w * 32 + mt * 16 + lr;
            int k   = kt * 32 + lg * 8;
            wf[mt][kt] = (k < 64) ? load_wfrag(w2_r, row, 64, k)
                                  : load_wfrag(w2_l, row, 64, k - 64);
        }

    {
        int e  = t >> 2, q = t & 3;
        int ng = base + e;
        if (q < 2) {
            const short* hp = (ng < N_NODES) ? (h1b + (size_t)ng * 64 + q * 32) : nullptr;
#pragma unroll
            for (int j = 0; j < 4; ++j) {
                short8 v = hp ? *(const short8*)(hp + j * 8) : (short8)0;
                int cc   = q * 4 + j;
                int scol = (cc * 8) ^ ((e & 7) << 3);
                *(short8*)&feat[e * 128 + scol] = v;
            }
        } else {
            float inv = 1.0f;
            const float* srcp = nullptr;
            if (ng < N_NODES) {
                int ci = cnt_i[ng];
                inv = 1.0f / (float)(ci > 0 ? ci : 1);
                srcp = s2 + (size_t)ng * 64 + (q - 2) * 32;
            }
#pragma unroll
            for (int j = 0; j < 4; ++j) {
                short8 v = (short8)0;
                if (srcp) {
                    f4 a = *(const f4*)(srcp + j * 8);
                    f4 b = *(const f4*)(srcp + j * 8 + 4);
#pragma unroll
                    for (int q2 = 0; q2 < 4; ++q2) { v[q2] = f2bf(a[q2] * inv); v[4 + q2] = f2bf(b[q2] * inv); }
                }
                int cc   = q * 4 + j;
                int scol = (cc * 8) ^ ((e & 7) << 3);
                *(short8*)&feat[e * 128 + scol] = v;
            }
        }
    }
    __syncthreads();

    f32x4 acc[2][4];
#pragma unroll
    for (int mt = 0; mt < 2; ++mt) {
        f4 bia = *(const f4*)&b2[w * 32 + mt * 16 + lg * 4];
#pragma unroll
        for (int nt = 0; nt < 4; ++nt) {
            acc[mt][nt][0] = bia[0]; acc[mt][nt][1] = bia[1];
            acc[mt][nt][2] = bia[2]; acc[mt][nt][3] = bia[3];
        }
    }
#pragma unroll
    for (int kt = 0; kt < 4; ++kt) {
        short8 bf[4];
#pragma unroll
        for (int nt = 0; nt < 4; ++nt) {
            int e = nt * 16 + lr;
            int k = kt * 32 + lg * 8;
            int scol = k ^ ((e & 7) << 3);
            bf[nt] = *(const short8*)&feat[e * 128 + scol];
        }
#pragma unroll
        for (int mt = 0; mt < 2; ++mt)
#pragma unroll
            for (int nt = 0; nt < 4; ++nt)
                acc[mt][nt] = MFMA16(wf[mt][kt], bf[nt], acc[mt][nt]);
    }
#pragma unroll
    for (int mt = 0; mt < 2; ++mt)
#pragma unroll
        for (int nt = 0; nt < 4; ++nt) {
            int ng = base + nt * 16 + lr;
            if (ng < N_NODES) {
                short4v o;
#pragma unroll
                for (int r = 0; r < 4; ++r) { float v = acc[mt][nt][r]; o[r] = f2bf(v > 0.0f ? v : 0.0f); }
                *(short4v*)&h2b[(size_t)ng * 128 + w * 32 + mt * 16 + lg * 4] = o;
            }
        }
}

// ---------------- fused edge MLP (unchanged from round 4) ----------------
__global__ __launch_bounds__(256, 3) void k_edge_fused(
    const short* __restrict__ h2b, const int* __restrict__ src,
    const int* __restrict__ dst, const int* __restrict__ y,
    const float* __restrict__ ow1, const float* __restrict__ ob1,
    const float* __restrict__ ow2, const float* __restrict__ ob2,
    const float* __restrict__ ow3, const float* __restrict__ ob3,
    const float* __restrict__ ow4, const float* __restrict__ ob4,
    const float* __restrict__ rw1, const float* __restrict__ rb1,
    const float* __restrict__ rw2, const float* __restrict__ rb2,
    const float* __restrict__ rw3, const float* __restrict__ rb3,
    float* __restrict__ out)
{
    __shared__ short feat[64 * 256];   // 32KB; act2/act3 alias after L1
    __shared__ short act1[64 * 128];   // 16KB; tail scratch aliases after L2
    __shared__ float sw[662];

    short* act2 = feat;
    short* act3 = feat + 64 * 64;
    float* tailf = (float*)act1;

    const int t    = threadIdx.x;
    const int w    = t >> 6;
    const int lane = t & 63;
    const int lr   = lane & 15;
    const int lg   = lane >> 4;

    if (t < 128) sw[t]       = ob1[t];
    if (t < 64)  sw[128 + t] = ob2[t];
    if (t < 32)  sw[192 + t] = ob3[t];
    if (t < 16)  sw[224 + t] = ob4[t];
    if (t < 8)   sw[240 + t] = rb1[t];
    if (t < 4)   sw[248 + t] = rb2[t];
    if (t < 50)  sw[252 + t] = rb3[t];
    if (t < 128) sw[302 + t] = rw1[t];
    if (t < 32)  sw[430 + t] = rw2[t];
    if (t < 200) sw[462 + t] = rw3[t];

    short8 w1f[2][8];
#pragma unroll
    for (int mt = 0; mt < 2; ++mt)
#pragma unroll
        for (int kt = 0; kt < 8; ++kt)
            w1f[mt][kt] = load_wfrag(ow1, w * 32 + mt * 16 + lr, 256, kt * 32 + lg * 8);

    short8 w2f[4];
#pragma unroll
    for (int kt = 0; kt < 4; ++kt)
        w2f[kt] = load_wfrag(ow2, w * 16 + lr, 128, kt * 32 + lg * 8);

    short8 w3f[2][2];
#pragma unroll
    for (int mt = 0; mt < 2; ++mt)
#pragma unroll
        for (int kt = 0; kt < 2; ++kt)
            w3f[mt][kt] = load_wfrag(ow3, mt * 16 + lr, 64, kt * 32 + lg * 8);

    short8 w4f = load_wfrag(ow4, lr, 32, lg * 8);

    for (int tile = blockIdx.x; tile < NTILES; tile += PBLOCKS) {
        const int base = tile * 64;

#pragma unroll
        for (int i = 0; i < 8; ++i) {
            int r0 = w * 16 + i * 2;
            int e  = r0 + (lane >> 5);
            int p  = lane & 31;
            int u  = p ^ (e & 7);
            int eg = base + e;
            int ec = eg < N_EDGES ? eg : 0;
            const int* ids = (u < 16) ? src : dst;
            int node = ids[ec];
            const short* g = h2b + (size_t)node * 128 + (u & 15) * 8;
            gload_lds16(g, &feat[r0 * 256]);
        }
        __syncthreads();

        {
            f32x4 acc[2][4];
#pragma unroll
            for (int mt = 0; mt < 2; ++mt) {
                f32x4 bia;
#pragma unroll
                for (int r = 0; r < 4; ++r) bia[r] = sw[w * 32 + mt * 16 + lg * 4 + r];
#pragma unroll
                for (int nt = 0; nt < 4; ++nt) acc[mt][nt] = bia;
            }
#pragma unroll
            for (int kt = 0; kt < 8; ++kt) {
                short8 bf[4];
#pragma unroll
                for (int nt = 0; nt < 4; ++nt) {
                    int e = nt * 16 + lr;
                    int k = kt * 32 + lg * 8;
                    int scol = k ^ ((e & 7) << 3);
                    bf[nt] = *(const short8*)&feat[e * 256 + scol];
                }
#pragma unroll
                for (int mt = 0; mt < 2; ++mt)
#pragma unroll
                    for (int nt = 0; nt < 4; ++nt)
                        acc[mt][nt] = MFMA16(w1f[mt][kt], bf[nt], acc[mt][nt]);
            }
#pragma unroll
            for (int mt = 0; mt < 2; ++mt)
#pragma unroll
                for (int nt = 0; nt < 4; ++nt) {
                    int e  = nt * 16 + lr;
                    int n0 = w * 32 + mt * 16 + lg * 4;
                    short4v s;
#pragma unroll
                    for (int r = 0; r < 4; ++r) {
                        float v = acc[mt][nt][r];
                        s[r] = f2bf(v > 0.0f ? v : 0.0f);
                    }
                    int scol = n0 ^ ((e & 7) << 3);
                    *(short4v*)&act1[e * 128 + scol] = s;
                }
        }
        __syncthreads();

        {
            f32x4 acc[4];
            f32x4 bia;
#pragma unroll
            for (int r = 0; r < 4; ++r) bia[r] = sw[128 + w * 16 + lg * 4 + r];
#pragma unroll
            for (int nt = 0; nt < 4; ++nt) acc[nt] = bia;
#pragma unroll
            for (int kt = 0; kt < 4; ++kt) {
#pragma unroll
                for (int nt = 0; nt < 4; ++nt) {
                    int e = nt * 16 + lr;
                    int k = kt * 32 + lg * 8;
                    int scol = k ^ ((e & 7) << 3);
                    short8 bf = *(const short8*)&act1[e * 128 + scol];
                    acc[nt] = MFMA16(w2f[kt], bf, acc[nt]);
                }
            }
#pragma unroll
            for (int nt = 0; nt < 4; ++nt) {
                int e  = nt * 16 + lr;
                int n0 = w * 16 + lg * 4;
                short4v s;
#pragma unroll
                for (int r = 0; r < 4; ++r) {
                    float v = acc[nt][r];
                    s[r] = f2bf(v > 0.0f ? v : 0.0f);
                }
                int scol = n0 ^ ((e & 7) << 3);
                *(short4v*)&act2[e * 64 + scol] = s;
            }
        }
        __syncthreads();

        {
            const int e3 = w * 16 + lr;
            float* T = tailf + w * 512;

            f32x4 acc[2];
#pragma unroll
            for (int mt = 0; mt < 2; ++mt)
#pragma unroll
                for (int r = 0; r < 4; ++r) acc[mt][r] = sw[192 + mt * 16 + lg * 4 + r];
#pragma unroll
            for (int kt = 0; kt < 2; ++kt) {
                int k = kt * 32 + lg * 8;
                int scol = k ^ ((e3 & 7) << 3);
                short8 bf = *(const short8*)&act2[e3 * 64 + scol];
#pragma unroll
                for (int mt = 0; mt < 2; ++mt)
                    acc[mt] = MFMA16(w3f[mt][kt], bf, acc[mt]);
            }
#pragma unroll
            for (int mt = 0; mt < 2; ++mt) {
                short4v s;
#pragma unroll
                for (int r = 0; r < 4; ++r) {
                    float v = acc[mt][r];
                    s[r] = f2bf(v > 0.0f ? v : 0.0f);
                }
                *(short4v*)&act3[e3 * 32 + mt * 16 + lg * 4] = s;
            }
            __builtin_amdgcn_wave_barrier();

            {
                short8 bf = *(const short8*)&act3[e3 * 32 + lg * 8];
                f32x4 a4;
#pragma unroll
                for (int r = 0; r < 4; ++r) a4[r] = sw[224 + lg * 4 + r];
                a4 = MFMA16(w4f, bf, a4);
#pragma unroll
                for (int r = 0; r < 4; ++r) T[lr * 17 + lg * 4 + r] = a4[r];
            }
            __builtin_amdgcn_wave_barrier();

            {
                float af[16];
#pragma unroll
                for (int f = 0; f < 16; ++f) af[f] = T[lr * 17 + f];
#pragma unroll
                for (int oo = 0; oo < 2; ++oo) {
                    int o = lg * 2 + oo;
                    float v = sw[240 + o];
#pragma unroll
                    for (int f = 0; f < 16; ++f) v += af[f] * sw[302 + o * 16 + f];
                    T[272 + lr * 9 + o] = v > 0.0f ? v : 0.0f;
                }
            }
            __builtin_amdgcn_wave_barrier();

            {
                float v = sw[248 + lg];
#pragma unroll
                for (int f = 0; f < 8; ++f) v += T[272 + lr * 9 + f] * sw[430 + lg * 8 + f];
                T[416 + lr * 5 + lg] = v > 0.0f ? v : 0.0f;
            }
            __builtin_amdgcn_wave_barrier();

            if (lane < 16) {
                int eg = base + w * 16 + lane;
                if (eg < N_EDGES) out[(size_t)N_EDGES * N_REL + eg] = (float)y[eg];
            }

            size_t obase = (size_t)(base + w * 16) * N_REL;
#pragma unroll
            for (int k2 = 0; k2 < 13; ++k2) {
                int idx = k2 * 64 + lane;
                if (idx < 16 * N_REL) {
                    int el = idx / N_REL;
                    int o  = idx - el * N_REL;
                    if (base + w * 16 + el < N_EDGES) {
                        float v = sw[252 + o];
#pragma unroll
                        for (int f = 0; f < 4; ++f) v += T[416 + el * 5 + f] * sw[462 + o * 4 + f];
                        out[obase + idx] = v;
                    }
                }
            }
        }
        __syncthreads();
    }
}

extern "C" void kernel_launch(void* const* d_in, const int* in_sizes, int n_in,
                              void* d_out, int out_size, void* d_ws, size_t ws_size,
                              hipStream_t stream) {
    const float* x    = (const float*)d_in[0];
    const int*   ei   = (const int*)d_in[1];
    const int*   src  = ei;
    const int*   dst  = ei + N_EDGES;
    const int*   y    = (const int*)d_in[2];
    const float* w1_l = (const float*)d_in[3];
    const float* b1   = (const float*)d_in[4];
    const float* w1_r = (const float*)d_in[5];
    const float* w2_l = (const float*)d_in[6];
    const float* b2   = (const float*)d_in[7];
    const float* w2_r = (const float*)d_in[8];
    const float* ow1  = (const float*)d_in[9];
    const float* ob1  = (const float*)d_in[10];
    const float* ow2  = (const float*)d_in[11];
    const float* ob2  = (const float*)d_in[12];
    const float* ow3  = (const float*)d_in[13];
    const float* ob3  = (const float*)d_in[14];
    const float* ow4  = (const float*)d_in[15];
    const float* ob4  = (const float*)d_in[16];
    const float* rw1  = (const float*)d_in[17];
    const float* rb1  = (const float*)d_in[18];
    const float* rw2  = (const float*)d_in[19];
    const float* rb2  = (const float*)d_in[20];
    const float* rw3  = (const float*)d_in[21];
    const float* rb3  = (const float*)d_in[22];

    float* ws     = (float*)d_ws;
    int*   cnt_i  = (int*)(ws + CNTI_OFF);
    int*   starts = (int*)(ws + STARTS_OFF);
    int*   cursor = (int*)(ws + CURSOR_OFF);
    int*   ebuf   = (int*)(ws + EBUF_OFF);
    float* s1     = ws + S1_OFF;
    float* s2     = ws + S2_OFF;
    short* h1b    = (short*)(ws + H1_OFF);
    short* h2b    = (short*)(ws + H2_OFF);
    float* out    = (float*)d_out;

    hipMemsetAsync(cnt_i, 0, N_NODES * sizeof(int), stream);

    k_hist  <<<(N_EDGES + 255) / 256, 256, 0, stream>>>(dst, cnt_i);
    k_scan  <<<1, 1024, 0, stream>>>(cnt_i, starts, cursor);
    k_bucket<<<(N_EDGES + 255) / 256, 256, 0, stream>>>(src, dst, cursor, ebuf);

    k_agg1<<<(N_NODES * 16 + 255) / 256, 256, 0, stream>>>(x, ebuf, starts, cnt_i, s1);
    k_sage1_mfma<<<NODE_TILES, 256, 0, stream>>>(x, s1, cnt_i, w1_l, b1, w1_r, h1b);

    k_agg2<<<(N_NODES * 64 + 255) / 256, 256, 0, stream>>>(h1b, ebuf, starts, cnt_i, s2);
    k_sage2_mfma<<<NODE_TILES, 256, 0, stream>>>(h1b, s2, cnt_i, w2_l, b2, w2_r, h2b);

    k_edge_fused<<<PBLOCKS, 256, 0, stream>>>(
        h2b, src, dst, y,
        ow1, ob1, ow2, ob2, ow3, ob3, ow4, ob4,
        rw1, rb1, rw2, rb2, rw3, rb3, out);
}

// Round 6
// 473.847 us; speedup vs baseline: 1.7027x; 1.1933x over previous
//
#include <hip/hip_runtime.h>
#include <hip/hip_bf16.h>

#define N_NODES 50000
#define N_EDGES 500000
#define N_REL   50
#define NTILES  ((N_EDGES + 63) / 64)   // 7813
#define EBLOCKS 1024
#define NODE_TILES ((N_NODES + 63) / 64)  // 782

// workspace layout (float-sized slots)
#define CNTI_OFF   0                          // int[50000]  (memset to 0)
#define STARTS_OFF (CNTI_OFF + N_NODES)
#define CURSOR_OFF (STARTS_OFF + N_NODES)
#define SRCB_OFF   (CURSOR_OFF + N_NODES)     // int[500000] src grouped by dst
#define DSTB_OFF   (SRCB_OFF + N_EDGES)       // int[500000] dst per position
#define EIDB_OFF   (DSTB_OFF + N_EDGES)       // int[500000] original edge id
#define S1_OFF     (EIDB_OFF + N_EDGES)       // float[50000*16]
#define S2_OFF     (S1_OFF + N_NODES*16)      // float[50000*64]; PRB (bf16) after sage2
#define H1_OFF     (S2_OFF + N_NODES*64)      // short[50000*64]  (bf16)
#define H2_OFF     (H1_OFF + N_NODES*32)      // short[50000*128] (bf16); PLB in-place
// end = H2_OFF + N_NODES*64 = 10.45M floats = 41.8 MB

typedef short short8  __attribute__((ext_vector_type(8)));
typedef short short4v __attribute__((ext_vector_type(4)));
typedef float f32x4   __attribute__((ext_vector_type(4)));
typedef float f4      __attribute__((ext_vector_type(4)));

#define MFMA16(a,b,c) __builtin_amdgcn_mfma_f32_16x16x32_bf16((a),(b),(c),0,0,0)

__device__ __forceinline__ short f2bf(float x) {
    unsigned u = __float_as_uint(x);
    unsigned r = (u + 0x7fffu + ((u >> 16) & 1u)) >> 16;   // RNE
    return (short)r;
}
__device__ __forceinline__ float bf2f(short s) {
    return __uint_as_float(((unsigned)(unsigned short)s) << 16);
}

__device__ __forceinline__ short8 load_wfrag(const float* __restrict__ W, int row, int K, int k) {
    const f4* p = (const f4*)(W + (size_t)row * K + k);
    f4 a = p[0], b = p[1];
    short8 r;
    r[0] = f2bf(a[0]); r[1] = f2bf(a[1]); r[2] = f2bf(a[2]); r[3] = f2bf(a[3]);
    r[4] = f2bf(b[0]); r[5] = f2bf(b[1]); r[6] = f2bf(b[2]); r[7] = f2bf(b[3]);
    return r;
}

// ---------------- CSR build: hist -> scan -> bucket ----------------

__global__ __launch_bounds__(256) void k_hist(
    const int* __restrict__ dst, int* __restrict__ cnt_i)
{
    int e = blockIdx.x * blockDim.x + threadIdx.x;
    if (e < N_EDGES) atomicAdd(&cnt_i[dst[e]], 1);
}

__global__ __launch_bounds__(1024) void k_scan(
    const int* __restrict__ cnt_i, int* __restrict__ starts, int* __restrict__ cursor)
{
    __shared__ int part[1024];
    const int i  = threadIdx.x;
    const int lo = i * 49;
    const int hi = min(N_NODES, lo + 49);
    int s = 0;
    for (int j = lo; j < hi; ++j) s += cnt_i[j];
    part[i] = s;
    __syncthreads();
    for (int d = 1; d < 1024; d <<= 1) {
        int v = (i >= d) ? part[i - d] : 0;
        __syncthreads();
        part[i] += v;
        __syncthreads();
    }
    int off = (i == 0) ? 0 : part[i - 1];
    for (int j = lo; j < hi; ++j) {
        starts[j] = off;
        cursor[j] = off;
        off += cnt_i[j];
    }
}

__global__ __launch_bounds__(256) void k_bucket(
    const int* __restrict__ src, const int* __restrict__ dst,
    int* __restrict__ cursor, int* __restrict__ srcb,
    int* __restrict__ dstb, int* __restrict__ eidb)
{
    int e = blockIdx.x * blockDim.x + threadIdx.x;
    if (e < N_EDGES) {
        int d = dst[e];
        int pos = atomicAdd(&cursor[d], 1);
        srcb[pos] = src[e];
        dstb[pos] = d;
        eidb[pos] = e;
    }
}

// ---------------- gather aggregation ----------------

__global__ __launch_bounds__(256) void k_agg1(
    const float* __restrict__ x, const int* __restrict__ ebuf,
    const int* __restrict__ starts, const int* __restrict__ cnt_i,
    float* __restrict__ s1)
{
    int t = blockIdx.x * blockDim.x + threadIdx.x;
    if (t >= N_NODES * 16) return;
    int n = t >> 4, f = t & 15;
    int st = starts[n], c = cnt_i[n];
    float s = 0.0f;
    for (int i = 0; i < c; ++i) s += x[(size_t)ebuf[st + i] * 16 + f];
    s1[t] = s;
}

__global__ __launch_bounds__(256) void k_agg2(
    const short* __restrict__ h1b, const int* __restrict__ ebuf,
    const int* __restrict__ starts, const int* __restrict__ cnt_i,
    float* __restrict__ s2)
{
    int t = blockIdx.x * blockDim.x + threadIdx.x;
    if (t >= N_NODES * 64) return;
    int n = t >> 6, f = t & 63;
    int st = starts[n], c = cnt_i[n];
    float s = 0.0f;
    for (int i = 0; i < c; ++i) s += bf2f(h1b[(size_t)ebuf[st + i] * 64 + f]);
    s2[t] = s;
}

// ---------------- SAGE1 via MFMA ----------------
__global__ __launch_bounds__(256) void k_sage1_mfma(
    const float* __restrict__ x, const float* __restrict__ s1,
    const int* __restrict__ cnt_i,
    const float* __restrict__ w1_l, const float* __restrict__ b1,
    const float* __restrict__ w1_r, short* __restrict__ h1b)
{
    __shared__ short feat[64 * 40];

    const int t    = threadIdx.x;
    const int w    = t >> 6;
    const int lane = t & 63;
    const int lr   = lane & 15;
    const int lg   = lane >> 4;
    const int base = blockIdx.x * 64;

    short8 w1f;
    if (lg < 2) w1f = load_wfrag(w1_l, w * 16 + lr, 16, lg * 8);
    else        w1f = load_wfrag(w1_r, w * 16 + lr, 16, (lg - 2) * 8);

    {
        int e  = t >> 2, q = t & 3;
        int ng = base + e;
        short8 v = (short8)0;
        if (ng < N_NODES) {
            if (q < 2) {
                int ci = cnt_i[ng];
                float inv = 1.0f / (float)(ci > 0 ? ci : 1);
                f4 a = *(const f4*)(s1 + (size_t)ng * 16 + q * 8);
                f4 b = *(const f4*)(s1 + (size_t)ng * 16 + q * 8 + 4);
#pragma unroll
                for (int j = 0; j < 4; ++j) { v[j] = f2bf(a[j] * inv); v[4 + j] = f2bf(b[j] * inv); }
            } else {
                f4 a = *(const f4*)(x + (size_t)ng * 16 + (q - 2) * 8);
                f4 b = *(const f4*)(x + (size_t)ng * 16 + (q - 2) * 8 + 4);
#pragma unroll
                for (int j = 0; j < 4; ++j) { v[j] = f2bf(a[j]); v[4 + j] = f2bf(b[j]); }
            }
        }
        *(short8*)&feat[e * 40 + q * 8] = v;
    }
    __syncthreads();

    f32x4 acc[4];
    f4 bia = *(const f4*)&b1[w * 16 + lg * 4];
#pragma unroll
    for (int nt = 0; nt < 4; ++nt) {
        acc[nt][0] = bia[0]; acc[nt][1] = bia[1]; acc[nt][2] = bia[2]; acc[nt][3] = bia[3];
    }
#pragma unroll
    for (int nt = 0; nt < 4; ++nt) {
        int e = nt * 16 + lr;
        short8 bf = *(const short8*)&feat[e * 40 + lg * 8];
        acc[nt] = MFMA16(w1f, bf, acc[nt]);
    }
#pragma unroll
    for (int nt = 0; nt < 4; ++nt) {
        int ng = base + nt * 16 + lr;
        if (ng < N_NODES) {
            short4v o;
#pragma unroll
            for (int r = 0; r < 4; ++r) { float v = acc[nt][r]; o[r] = f2bf(v > 0.0f ? v : 0.0f); }
            *(short4v*)&h1b[(size_t)ng * 64 + w * 16 + lg * 4] = o;
        }
    }
}

// ---------------- SAGE2 via MFMA ----------------
__global__ __launch_bounds__(256) void k_sage2_mfma(
    const short* __restrict__ h1b, const float* __restrict__ s2,
    const int* __restrict__ cnt_i,
    const float* __restrict__ w2_l, const float* __restrict__ b2,
    const float* __restrict__ w2_r, short* __restrict__ h2b)
{
    __shared__ short feat[64 * 128];

    const int t    = threadIdx.x;
    const int w    = t >> 6;
    const int lane = t & 63;
    const int lr   = lane & 15;
    const int lg   = lane >> 4;
    const int base = blockIdx.x * 64;

    short8 wf[2][4];
#pragma unroll
    for (int mt = 0; mt < 2; ++mt)
#pragma unroll
        for (int kt = 0; kt < 4; ++kt) {
            int row = w * 32 + mt * 16 + lr;
            int k   = kt * 32 + lg * 8;
            wf[mt][kt] = (k < 64) ? load_wfrag(w2_r, row, 64, k)
                                  : load_wfrag(w2_l, row, 64, k - 64);
        }

    {
        int e  = t >> 2, q = t & 3;
        int ng = base + e;
        if (q < 2) {
            const short* hp = (ng < N_NODES) ? (h1b + (size_t)ng * 64 + q * 32) : nullptr;
#pragma unroll
            for (int j = 0; j < 4; ++j) {
                short8 v = hp ? *(const short8*)(hp + j * 8) : (short8)0;
                int cc   = q * 4 + j;
                int scol = (cc * 8) ^ ((e & 7) << 3);
                *(short8*)&feat[e * 128 + scol] = v;
            }
        } else {
            float inv = 1.0f;
            const float* srcp = nullptr;
            if (ng < N_NODES) {
                int ci = cnt_i[ng];
                inv = 1.0f / (float)(ci > 0 ? ci : 1);
                srcp = s2 + (size_t)ng * 64 + (q - 2) * 32;
            }
#pragma unroll
            for (int j = 0; j < 4; ++j) {
                short8 v = (short8)0;
                if (srcp) {
                    f4 a = *(const f4*)(srcp + j * 8);
                    f4 b = *(const f4*)(srcp + j * 8 + 4);
#pragma unroll
                    for (int q2 = 0; q2 < 4; ++q2) { v[q2] = f2bf(a[q2] * inv); v[4 + q2] = f2bf(b[q2] * inv); }
                }
                int cc   = q * 4 + j;
                int scol = (cc * 8) ^ ((e & 7) << 3);
                *(short8*)&feat[e * 128 + scol] = v;
            }
        }
    }
    __syncthreads();

    f32x4 acc[2][4];
#pragma unroll
    for (int mt = 0; mt < 2; ++mt) {
        f4 bia = *(const f4*)&b2[w * 32 + mt * 16 + lg * 4];
#pragma unroll
        for (int nt = 0; nt < 4; ++nt) {
            acc[mt][nt][0] = bia[0]; acc[mt][nt][1] = bia[1];
            acc[mt][nt][2] = bia[2]; acc[mt][nt][3] = bia[3];
        }
    }
#pragma unroll
    for (int kt = 0; kt < 4; ++kt) {
        short8 bf[4];
#pragma unroll
        for (int nt = 0; nt < 4; ++nt) {
            int e = nt * 16 + lr;
            int k = kt * 32 + lg * 8;
            int scol = k ^ ((e & 7) << 3);
            bf[nt] = *(const short8*)&feat[e * 128 + scol];
        }
#pragma unroll
        for (int mt = 0; mt < 2; ++mt)
#pragma unroll
            for (int nt = 0; nt < 4; ++nt)
                acc[mt][nt] = MFMA16(wf[mt][kt], bf[nt], acc[mt][nt]);
    }
#pragma unroll
    for (int mt = 0; mt < 2; ++mt)
#pragma unroll
        for (int nt = 0; nt < 4; ++nt) {
            int ng = base + nt * 16 + lr;
            if (ng < N_NODES) {
                short4v o;
#pragma unroll
                for (int r = 0; r < 4; ++r) { float v = acc[mt][nt][r]; o[r] = f2bf(v > 0.0f ? v : 0.0f); }
                *(short4v*)&h2b[(size_t)ng * 128 + w * 32 + mt * 16 + lg * 4] = o;
            }
        }
}

// ---------------- proj: PL = h2 @ ow1[:, :128].T ; PR = h2 @ ow1[:, 128:].T --
// Writes PL in-place over h2b (same rows as staged; safe after __syncthreads),
// PR into prb. No bias (added in edge staging). Wave w<2: PL rows [w*64,w*64+64);
// w>=2: PR rows [(w-2)*64, ...).
__global__ __launch_bounds__(256) void k_proj(
    const short* __restrict__ h2b, const float* __restrict__ ow1,
    short* __restrict__ plb, short* __restrict__ prb)
{
    __shared__ short feat[64 * 128];

    const int t    = threadIdx.x;
    const int w    = t >> 6;
    const int lane = t & 63;
    const int lr   = lane & 15;
    const int lg   = lane >> 4;
    const int base = blockIdx.x * 64;
    const int isR  = (w >= 2);
    const int rb0  = (w & 1) * 64;         // row base within PL or PR

    short8 wf[4][4];
#pragma unroll
    for (int mt = 0; mt < 4; ++mt)
#pragma unroll
        for (int kt = 0; kt < 4; ++kt) {
            int row = rb0 + mt * 16 + lr;
            int k   = kt * 32 + lg * 8 + (isR ? 128 : 0);
            wf[mt][kt] = load_wfrag(ow1, row, 256, k);
        }

    {
        int e  = t >> 2, q = t & 3;
        int ng = base + e;
        const short* hp = (ng < N_NODES) ? (h2b + (size_t)ng * 128 + q * 32) : nullptr;
#pragma unroll
        for (int j = 0; j < 4; ++j) {
            short8 v = hp ? *(const short8*)(hp + j * 8) : (short8)0;
            int k0   = q * 32 + j * 8;
            int scol = k0 ^ ((e & 7) << 3);
            *(short8*)&feat[e * 128 + scol] = v;
        }
    }
    __syncthreads();

    f32x4 acc[4][4];
#pragma unroll
    for (int mt = 0; mt < 4; ++mt)
#pragma unroll
        for (int nt = 0; nt < 4; ++nt)
            acc[mt][nt] = (f32x4)0.0f;
#pragma unroll
    for (int kt = 0; kt < 4; ++kt) {
        short8 bf[4];
#pragma unroll
        for (int nt = 0; nt < 4; ++nt) {
            int e = nt * 16 + lr;
            int k = kt * 32 + lg * 8;
            int scol = k ^ ((e & 7) << 3);
            bf[nt] = *(const short8*)&feat[e * 128 + scol];
        }
#pragma unroll
        for (int mt = 0; mt < 4; ++mt)
#pragma unroll
            for (int nt = 0; nt < 4; ++nt)
                acc[mt][nt] = MFMA16(wf[mt][kt], bf[nt], acc[mt][nt]);
    }
    short* outp = isR ? prb : plb;
#pragma unroll
    for (int mt = 0; mt < 4; ++mt)
#pragma unroll
        for (int nt = 0; nt < 4; ++nt) {
            int ng = base + nt * 16 + lr;
            if (ng < N_NODES) {
                short4v o;
#pragma unroll
                for (int r = 0; r < 4; ++r) o[r] = f2bf(acc[mt][nt][r]);
                *(short4v*)&outp[(size_t)ng * 128 + rb0 + mt * 16 + lg * 4] = o;
            }
        }
}

__global__ __launch_bounds__(256) void k_ycopy(
    const int* __restrict__ y, float* __restrict__ out)
{
    int e = blockIdx.x * blockDim.x + threadIdx.x;
    if (e < N_EDGES) out[(size_t)N_EDGES * N_REL + e] = (float)y[e];
}

// ---------------- fused edge MLP v2: bucketed edges, no L1 GEMM ----------------
// a1[e] = relu(PL[src] + PR[dst] + ob1) computed in staging; L2/L3/L4/tail as before.
// Outputs scattered to original edge ids via eidb.
__global__ __launch_bounds__(256, 4) void k_edge2(
    const short* __restrict__ plb, const short* __restrict__ prb,
    const int* __restrict__ srcb, const int* __restrict__ dstb,
    const int* __restrict__ eidb,
    const float* __restrict__ ob1,
    const float* __restrict__ ow2, const float* __restrict__ ob2,
    const float* __restrict__ ow3, const float* __restrict__ ob3,
    const float* __restrict__ ow4, const float* __restrict__ ob4,
    const float* __restrict__ rw1, const float* __restrict__ rb1,
    const float* __restrict__ rw2, const float* __restrict__ rb2,
    const float* __restrict__ rw3, const float* __restrict__ rb3,
    float* __restrict__ out)
{
    __shared__ short a1s[64 * 128];    // 16KB; tail T aliases after L2
    __shared__ short actB[64 * 96];    // act2 [64*64] | act3 [64*32]
    __shared__ float sw[662];
    __shared__ int   eidsh[64];

    short* act2  = actB;
    short* act3  = actB + 64 * 64;
    float* tailf = (float*)a1s;

    const int t    = threadIdx.x;
    const int w    = t >> 6;
    const int lane = t & 63;
    const int lr   = lane & 15;
    const int lg   = lane >> 4;

    if (t < 128) sw[t]       = ob1[t];
    if (t < 64)  sw[128 + t] = ob2[t];
    if (t < 32)  sw[192 + t] = ob3[t];
    if (t < 16)  sw[224 + t] = ob4[t];
    if (t < 8)   sw[240 + t] = rb1[t];
    if (t < 4)   sw[248 + t] = rb2[t];
    if (t < 50)  sw[252 + t] = rb3[t];
    if (t < 128) sw[302 + t] = rw1[t];
    if (t < 32)  sw[430 + t] = rw2[t];
    if (t < 200) sw[462 + t] = rw3[t];

    short8 w2f[4];
#pragma unroll
    for (int kt = 0; kt < 4; ++kt)
        w2f[kt] = load_wfrag(ow2, w * 16 + lr, 128, kt * 32 + lg * 8);

    short8 w3f[2][2];
#pragma unroll
    for (int mt = 0; mt < 2; ++mt)
#pragma unroll
        for (int kt = 0; kt < 2; ++kt)
            w3f[mt][kt] = load_wfrag(ow3, mt * 16 + lr, 64, kt * 32 + lg * 8);

    short8 w4f = load_wfrag(ow4, lr, 32, lg * 8);

    __syncthreads();   // sw ready before first staging reads it

    for (int tile = blockIdx.x; tile < NTILES; tile += EBLOCKS) {
        const int base = tile * 64;

        // ---- stage a1 = relu(PL[src] + PR[dst] + ob1), swizzled bf16 ----
        {
            int e = t >> 2, p = t & 3;
            int pos  = base + e;
            int posc = pos < N_EDGES ? pos : 0;
            int sn = srcb[posc], dn = dstb[posc];
            const short* pl = plb + (size_t)sn * 128 + p * 32;
            const short* pr = prb + (size_t)dn * 128 + p * 32;
#pragma unroll
            for (int j = 0; j < 4; ++j) {
                short8 vl = *(const short8*)(pl + j * 8);
                short8 vr = *(const short8*)(pr + j * 8);
                short8 s;
#pragma unroll
                for (int i = 0; i < 8; ++i) {
                    float v = bf2f(vl[i]) + bf2f(vr[i]) + sw[p * 32 + j * 8 + i];
                    s[i] = f2bf(v > 0.0f ? v : 0.0f);
                }
                int k0 = p * 32 + j * 8;
                int scol = k0 ^ ((e & 7) << 3);
                *(short8*)&a1s[e * 128 + scol] = s;
            }
            if (t < 64) {
                int pos2 = base + t;
                eidsh[t] = (pos2 < N_EDGES) ? eidb[pos2] : -1;
            }
        }
        __syncthreads();

        // ---- L2: 128 -> 64, relu ----
        {
            f32x4 acc[4];
            f32x4 bia;
#pragma unroll
            for (int r = 0; r < 4; ++r) bia[r] = sw[128 + w * 16 + lg * 4 + r];
#pragma unroll
            for (int nt = 0; nt < 4; ++nt) acc[nt] = bia;
#pragma unroll
            for (int kt = 0; kt < 4; ++kt) {
#pragma unroll
                for (int nt = 0; nt < 4; ++nt) {
                    int e = nt * 16 + lr;
                    int k = kt * 32 + lg * 8;
                    int scol = k ^ ((e & 7) << 3);
                    short8 bf = *(const short8*)&a1s[e * 128 + scol];
                    acc[nt] = MFMA16(w2f[kt], bf, acc[nt]);
                }
            }
#pragma unroll
            for (int nt = 0; nt < 4; ++nt) {
                int e  = nt * 16 + lr;
                int n0 = w * 16 + lg * 4;
                short4v s;
#pragma unroll
                for (int r = 0; r < 4; ++r) {
                    float v = acc[nt][r];
                    s[r] = f2bf(v > 0.0f ? v : 0.0f);
                }
                int scol = n0 ^ ((e & 7) << 3);
                *(short4v*)&act2[e * 64 + scol] = s;
            }
        }
        __syncthreads();   // act2 ready; a1s dead -> tail T may alias

        // ---- wave-local tail: L3, L4, rf1, rf2, rf3 ----
        {
            const int e3 = w * 16 + lr;
            float* T = tailf + w * 512;

            f32x4 acc[2];
#pragma unroll
            for (int mt = 0; mt < 2; ++mt)
#pragma unroll
                for (int r = 0; r < 4; ++r) acc[mt][r] = sw[192 + mt * 16 + lg * 4 + r];
#pragma unroll
            for (int kt = 0; kt < 2; ++kt) {
                int k = kt * 32 + lg * 8;
                int scol = k ^ ((e3 & 7) << 3);
                short8 bf = *(const short8*)&act2[e3 * 64 + scol];
#pragma unroll
                for (int mt = 0; mt < 2; ++mt)
                    acc[mt] = MFMA16(w3f[mt][kt], bf, acc[mt]);
            }
#pragma unroll
            for (int mt = 0; mt < 2; ++mt) {
                short4v s;
#pragma unroll
                for (int r = 0; r < 4; ++r) {
                    float v = acc[mt][r];
                    s[r] = f2bf(v > 0.0f ? v : 0.0f);
                }
                *(short4v*)&act3[e3 * 32 + mt * 16 + lg * 4] = s;
            }
            __builtin_amdgcn_wave_barrier();

            {
                short8 bf = *(const short8*)&act3[e3 * 32 + lg * 8];
                f32x4 a4;
#pragma unroll
                for (int r = 0; r < 4; ++r) a4[r] = sw[224 + lg * 4 + r];
                a4 = MFMA16(w4f, bf, a4);
#pragma unroll
                for (int r = 0; r < 4; ++r) T[lr * 17 + lg * 4 + r] = a4[r];
            }
            __builtin_amdgcn_wave_barrier();

            {
                float af[16];
#pragma unroll
                for (int f = 0; f < 16; ++f) af[f] = T[lr * 17 + f];
#pragma unroll
                for (int oo = 0; oo < 2; ++oo) {
                    int o = lg * 2 + oo;
                    float v = sw[240 + o];
#pragma unroll
                    for (int f = 0; f < 16; ++f) v += af[f] * sw[302 + o * 16 + f];
                    T[272 + lr * 9 + o] = v > 0.0f ? v : 0.0f;
                }
            }
            __builtin_amdgcn_wave_barrier();

            {
                float v = sw[248 + lg];
#pragma unroll
                for (int f = 0; f < 8; ++f) v += T[272 + lr * 9 + f] * sw[430 + lg * 8 + f];
                T[416 + lr * 5 + lg] = v > 0.0f ? v : 0.0f;
            }
            __builtin_amdgcn_wave_barrier();

            // rf3: 4 -> 50, scattered by original edge id
#pragma unroll
            for (int k2 = 0; k2 < 13; ++k2) {
                int idx = k2 * 64 + lane;
                if (idx < 16 * N_REL) {
                    int el = idx / N_REL;
                    int o  = idx - el * N_REL;
                    int eid = eidsh[w * 16 + el];
                    if (eid >= 0) {
                        float v = sw[252 + o];
#pragma unroll
                        for (int f = 0; f < 4; ++f) v += T[416 + el * 5 + f] * sw[462 + o * 4 + f];
                        out[(size_t)eid * N_REL + o] = v;
                    }
                }
            }
        }
        __syncthreads();
    }
}

extern "C" void kernel_launch(void* const* d_in, const int* in_sizes, int n_in,
                              void* d_out, int out_size, void* d_ws, size_t ws_size,
                              hipStream_t stream) {
    const float* x    = (const float*)d_in[0];
    const int*   ei   = (const int*)d_in[1];
    const int*   src  = ei;
    const int*   dst  = ei + N_EDGES;
    const int*   y    = (const int*)d_in[2];
    const float* w1_l = (const float*)d_in[3];
    const float* b1   = (const float*)d_in[4];
    const float* w1_r = (const float*)d_in[5];
    const float* w2_l = (const float*)d_in[6];
    const float* b2   = (const float*)d_in[7];
    const float* w2_r = (const float*)d_in[8];
    const float* ow1  = (const float*)d_in[9];
    const float* ob1  = (const float*)d_in[10];
    const float* ow2  = (const float*)d_in[11];
    const float* ob2  = (const float*)d_in[12];
    const float* ow3  = (const float*)d_in[13];
    const float* ob3  = (const float*)d_in[14];
    const float* ow4  = (const float*)d_in[15];
    const float* ob4  = (const float*)d_in[16];
    const float* rw1  = (const float*)d_in[17];
    const float* rb1  = (const float*)d_in[18];
    const float* rw2  = (const float*)d_in[19];
    const float* rb2  = (const float*)d_in[20];
    const float* rw3  = (const float*)d_in[21];
    const float* rb3  = (const float*)d_in[22];

    float* ws     = (float*)d_ws;
    int*   cnt_i  = (int*)(ws + CNTI_OFF);
    int*   starts = (int*)(ws + STARTS_OFF);
    int*   cursor = (int*)(ws + CURSOR_OFF);
    int*   srcb   = (int*)(ws + SRCB_OFF);
    int*   dstb   = (int*)(ws + DSTB_OFF);
    int*   eidb   = (int*)(ws + EIDB_OFF);
    float* s1     = ws + S1_OFF;
    float* s2     = ws + S2_OFF;
    short* h1b    = (short*)(ws + H1_OFF);
    short* h2b    = (short*)(ws + H2_OFF);
    short* plb    = h2b;                   // PL overwrites h2b in-place (k_proj)
    short* prb    = (short*)(ws + S2_OFF); // PR over dead s2
    float* out    = (float*)d_out;

    hipMemsetAsync(cnt_i, 0, N_NODES * sizeof(int), stream);

    k_hist  <<<(N_EDGES + 255) / 256, 256, 0, stream>>>(dst, cnt_i);
    k_scan  <<<1, 1024, 0, stream>>>(cnt_i, starts, cursor);
    k_bucket<<<(N_EDGES + 255) / 256, 256, 0, stream>>>(src, dst, cursor, srcb, dstb, eidb);

    k_agg1<<<(N_NODES * 16 + 255) / 256, 256, 0, stream>>>(x, srcb, starts, cnt_i, s1);
    k_sage1_mfma<<<NODE_TILES, 256, 0, stream>>>(x, s1, cnt_i, w1_l, b1, w1_r, h1b);

    k_agg2<<<(N_NODES * 64 + 255) / 256, 256, 0, stream>>>(h1b, srcb, starts, cnt_i, s2);
    k_sage2_mfma<<<NODE_TILES, 256, 0, stream>>>(h1b, s2, cnt_i, w2_l, b2, w2_r, h2b);

    k_proj<<<NODE_TILES, 256, 0, stream>>>(h2b, ow1, plb, prb);
    k_ycopy<<<(N_EDGES + 255) / 256, 256, 0, stream>>>(y, out);

    k_edge2<<<EBLOCKS, 256, 0, stream>>>(
        plb, prb, srcb, dstb, eidb,
        ob1, ow2, ob2, ow3, ob3, ow4, ob4,
        rw1, rb1, rw2, rb2, rw3, rb3, out);
}

// Round 7
// 446.452 us; speedup vs baseline: 1.8072x; 1.0614x over previous
//
#include <hip/hip_runtime.h>
#include <hip/hip_bf16.h>

#define N_NODES 50000
#define N_EDGES 500000
#define N_REL   50
#define NTILES  ((N_EDGES + 63) / 64)   // 7813
#define EBLOCKS 1024
#define NODE_TILES ((N_NODES + 63) / 64)  // 782

// workspace layout (float-sized slots)
#define CNTI_OFF   0                          // int[50000]  (memset to 0)
#define STARTS_OFF (CNTI_OFF + N_NODES)
#define CURSOR_OFF (STARTS_OFF + N_NODES)
#define SRCB_OFF   (CURSOR_OFF + N_NODES)     // int[500000] src grouped by dst
#define S1_OFF     (SRCB_OFF + N_EDGES)       // float[50000*16]
#define S2_OFF     (S1_OFF + N_NODES*16)      // float[50000*64]; PRB (bf16) after sage2p
#define H1_OFF     (S2_OFF + N_NODES*64)      // short[50000*64]  (bf16)
#define H2_OFF     (H1_OFF + N_NODES*32)      // short[50000*128] = PLB
// end = H2_OFF + N_NODES*64 = 9.45M floats = 37.8 MB

typedef short short8  __attribute__((ext_vector_type(8)));
typedef short short4v __attribute__((ext_vector_type(4)));
typedef float f32x4   __attribute__((ext_vector_type(4)));
typedef float f4      __attribute__((ext_vector_type(4)));

#define MFMA16(a,b,c) __builtin_amdgcn_mfma_f32_16x16x32_bf16((a),(b),(c),0,0,0)

__device__ __forceinline__ short f2bf(float x) {
    unsigned u = __float_as_uint(x);
    unsigned r = (u + 0x7fffu + ((u >> 16) & 1u)) >> 16;   // RNE
    return (short)r;
}
__device__ __forceinline__ float bf2f(short s) {
    return __uint_as_float(((unsigned)(unsigned short)s) << 16);
}

__device__ __forceinline__ short8 load_wfrag(const float* __restrict__ W, int row, int K, int k) {
    const f4* p = (const f4*)(W + (size_t)row * K + k);
    f4 a = p[0], b = p[1];
    short8 r;
    r[0] = f2bf(a[0]); r[1] = f2bf(a[1]); r[2] = f2bf(a[2]); r[3] = f2bf(a[3]);
    r[4] = f2bf(b[0]); r[5] = f2bf(b[1]); r[6] = f2bf(b[2]); r[7] = f2bf(b[3]);
    return r;
}

// ---------------- CSR build: hist -> scan -> bucket ----------------

__global__ __launch_bounds__(256) void k_hist(
    const int* __restrict__ dst, int* __restrict__ cnt_i)
{
    int e = blockIdx.x * blockDim.x + threadIdx.x;
    if (e < N_EDGES) atomicAdd(&cnt_i[dst[e]], 1);
}

__global__ __launch_bounds__(1024) void k_scan(
    const int* __restrict__ cnt_i, int* __restrict__ starts, int* __restrict__ cursor)
{
    __shared__ int part[1024];
    const int i  = threadIdx.x;
    const int lo = i * 49;
    const int hi = min(N_NODES, lo + 49);
    int s = 0;
    for (int j = lo; j < hi; ++j) s += cnt_i[j];
    part[i] = s;
    __syncthreads();
    for (int d = 1; d < 1024; d <<= 1) {
        int v = (i >= d) ? part[i - d] : 0;
        __syncthreads();
        part[i] += v;
        __syncthreads();
    }
    int off = (i == 0) ? 0 : part[i - 1];
    for (int j = lo; j < hi; ++j) {
        starts[j] = off;
        cursor[j] = off;
        off += cnt_i[j];
    }
}

__global__ __launch_bounds__(256) void k_bucket(
    const int* __restrict__ src, const int* __restrict__ dst,
    int* __restrict__ cursor, int* __restrict__ srcb)
{
    int e = blockIdx.x * blockDim.x + threadIdx.x;
    if (e < N_EDGES) {
        int pos = atomicAdd(&cursor[dst[e]], 1);
        srcb[pos] = src[e];
    }
}

// ---------------- gather aggregation ----------------

__global__ __launch_bounds__(256) void k_agg1(
    const float* __restrict__ x, const int* __restrict__ ebuf,
    const int* __restrict__ starts, const int* __restrict__ cnt_i,
    float* __restrict__ s1)
{
    int t = blockIdx.x * blockDim.x + threadIdx.x;
    if (t >= N_NODES * 16) return;
    int n = t >> 4, f = t & 15;
    int st = starts[n], c = cnt_i[n];
    float s = 0.0f;
    for (int i = 0; i < c; ++i) s += x[(size_t)ebuf[st + i] * 16 + f];
    s1[t] = s;
}

__global__ __launch_bounds__(256) void k_agg2(
    const short* __restrict__ h1b, const int* __restrict__ ebuf,
    const int* __restrict__ starts, const int* __restrict__ cnt_i,
    float* __restrict__ s2)
{
    int t = blockIdx.x * blockDim.x + threadIdx.x;
    if (t >= N_NODES * 64) return;
    int n = t >> 6, f = t & 63;
    int st = starts[n], c = cnt_i[n];
    float s = 0.0f;
    for (int i = 0; i < c; ++i) s += bf2f(h1b[(size_t)ebuf[st + i] * 64 + f]);
    s2[t] = s;
}

// ---------------- SAGE1 via MFMA ----------------
__global__ __launch_bounds__(256) void k_sage1_mfma(
    const float* __restrict__ x, const float* __restrict__ s1,
    const int* __restrict__ cnt_i,
    const float* __restrict__ w1_l, const float* __restrict__ b1,
    const float* __restrict__ w1_r, short* __restrict__ h1b)
{
    __shared__ short feat[64 * 40];

    const int t    = threadIdx.x;
    const int w    = t >> 6;
    const int lane = t & 63;
    const int lr   = lane & 15;
    const int lg   = lane >> 4;
    const int base = blockIdx.x * 64;

    short8 w1f;
    if (lg < 2) w1f = load_wfrag(w1_l, w * 16 + lr, 16, lg * 8);
    else        w1f = load_wfrag(w1_r, w * 16 + lr, 16, (lg - 2) * 8);

    {
        int e  = t >> 2, q = t & 3;
        int ng = base + e;
        short8 v = (short8)0;
        if (ng < N_NODES) {
            if (q < 2) {
                int ci = cnt_i[ng];
                float inv = 1.0f / (float)(ci > 0 ? ci : 1);
                f4 a = *(const f4*)(s1 + (size_t)ng * 16 + q * 8);
                f4 b = *(const f4*)(s1 + (size_t)ng * 16 + q * 8 + 4);
#pragma unroll
                for (int j = 0; j < 4; ++j) { v[j] = f2bf(a[j] * inv); v[4 + j] = f2bf(b[j] * inv); }
            } else {
                f4 a = *(const f4*)(x + (size_t)ng * 16 + (q - 2) * 8);
                f4 b = *(const f4*)(x + (size_t)ng * 16 + (q - 2) * 8 + 4);
#pragma unroll
                for (int j = 0; j < 4; ++j) { v[j] = f2bf(a[j]); v[4 + j] = f2bf(b[j]); }
            }
        }
        *(short8*)&feat[e * 40 + q * 8] = v;
    }
    __syncthreads();

    f32x4 acc[4];
    f4 bia = *(const f4*)&b1[w * 16 + lg * 4];
#pragma unroll
    for (int nt = 0; nt < 4; ++nt) {
        acc[nt][0] = bia[0]; acc[nt][1] = bia[1]; acc[nt][2] = bia[2]; acc[nt][3] = bia[3];
    }
#pragma unroll
    for (int nt = 0; nt < 4; ++nt) {
        int e = nt * 16 + lr;
        short8 bf = *(const short8*)&feat[e * 40 + lg * 8];
        acc[nt] = MFMA16(w1f, bf, acc[nt]);
    }
#pragma unroll
    for (int nt = 0; nt < 4; ++nt) {
        int ng = base + nt * 16 + lr;
        if (ng < N_NODES) {
            short4v o;
#pragma unroll
            for (int r = 0; r < 4; ++r) { float v = acc[nt][r]; o[r] = f2bf(v > 0.0f ? v : 0.0f); }
            *(short4v*)&h1b[(size_t)ng * 64 + w * 16 + lg * 4] = o;
        }
    }
}

// ---------------- SAGE2 + proj fused: h2 lives only in LDS ----------------
// Phase A (sage2): acc = relu(W2cat·[h1||mean] + b2) -> feat2 (bf16, swizzled).
// Phase B (proj): PL = h2·ow1[:, :128]^T, PR = h2·ow1[:, 128:]^T (no bias),
// written bf16 to plb/prb. Wave w owns out rows [w*32, w*32+32) in all GEMMs.
// prb aliases s2's memory: each block reads s2 rows of its own nodes during
// staging (before barrier) and overwrites exactly those rows after -> safe.
__global__ __launch_bounds__(256) void k_sage2p(
    const short* __restrict__ h1b, const float* __restrict__ s2,
    const int* __restrict__ cnt_i,
    const float* __restrict__ w2_l, const float* __restrict__ b2,
    const float* __restrict__ w2_r, const float* __restrict__ ow1,
    short* __restrict__ plb, short* __restrict__ prb)
{
    __shared__ short feat[64 * 128];
    __shared__ short feat2[64 * 128];

    const int t    = threadIdx.x;
    const int w    = t >> 6;
    const int lane = t & 63;
    const int lr   = lane & 15;
    const int lg   = lane >> 4;
    const int base = blockIdx.x * 64;

    short8 wf[2][4];
#pragma unroll
    for (int mt = 0; mt < 2; ++mt)
#pragma unroll
        for (int kt = 0; kt < 4; ++kt) {
            int row = w * 32 + mt * 16 + lr;
            int k   = kt * 32 + lg * 8;
            wf[mt][kt] = (k < 64) ? load_wfrag(w2_r, row, 64, k)
                                  : load_wfrag(w2_l, row, 64, k - 64);
        }

    {
        int e  = t >> 2, q = t & 3;
        int ng = base + e;
        if (q < 2) {
            const short* hp = (ng < N_NODES) ? (h1b + (size_t)ng * 64 + q * 32) : nullptr;
#pragma unroll
            for (int j = 0; j < 4; ++j) {
                short8 v = hp ? *(const short8*)(hp + j * 8) : (short8)0;
                int scol = (q * 32 + j * 8) ^ ((e & 7) << 3);
                *(short8*)&feat[e * 128 + scol] = v;
            }
        } else {
            float inv = 1.0f;
            const float* srcp = nullptr;
            if (ng < N_NODES) {
                int ci = cnt_i[ng];
                inv = 1.0f / (float)(ci > 0 ? ci : 1);
                srcp = s2 + (size_t)ng * 64 + (q - 2) * 32;
            }
#pragma unroll
            for (int j = 0; j < 4; ++j) {
                short8 v = (short8)0;
                if (srcp) {
                    f4 a = *(const f4*)(srcp + j * 8);
                    f4 b = *(const f4*)(srcp + j * 8 + 4);
#pragma unroll
                    for (int q2 = 0; q2 < 4; ++q2) { v[q2] = f2bf(a[q2] * inv); v[4 + q2] = f2bf(b[q2] * inv); }
                }
                int scol = ((q - 2) * 32 + 64 + j * 8) ^ ((e & 7) << 3);
                *(short8*)&feat[e * 128 + scol] = v;
            }
        }
    }
    __syncthreads();

    // phase A: h2 tile
    {
        f32x4 acc[2][4];
#pragma unroll
        for (int mt = 0; mt < 2; ++mt) {
            f4 bia = *(const f4*)&b2[w * 32 + mt * 16 + lg * 4];
#pragma unroll
            for (int nt = 0; nt < 4; ++nt) {
                acc[mt][nt][0] = bia[0]; acc[mt][nt][1] = bia[1];
                acc[mt][nt][2] = bia[2]; acc[mt][nt][3] = bia[3];
            }
        }
#pragma unroll
        for (int kt = 0; kt < 4; ++kt) {
            short8 bf[4];
#pragma unroll
            for (int nt = 0; nt < 4; ++nt) {
                int e = nt * 16 + lr;
                int scol = (kt * 32 + lg * 8) ^ ((e & 7) << 3);
                bf[nt] = *(const short8*)&feat[e * 128 + scol];
            }
#pragma unroll
            for (int mt = 0; mt < 2; ++mt)
#pragma unroll
                for (int nt = 0; nt < 4; ++nt)
                    acc[mt][nt] = MFMA16(wf[mt][kt], bf[nt], acc[mt][nt]);
        }
#pragma unroll
        for (int mt = 0; mt < 2; ++mt)
#pragma unroll
            for (int nt = 0; nt < 4; ++nt) {
                int e  = nt * 16 + lr;
                int n0 = w * 32 + mt * 16 + lg * 4;
                short4v s;
#pragma unroll
                for (int r = 0; r < 4; ++r) {
                    float v = acc[mt][nt][r];
                    s[r] = f2bf(v > 0.0f ? v : 0.0f);
                }
                *(short4v*)&feat2[e * 128 + (n0 ^ ((e & 7) << 3))] = s;
            }
    }
    __syncthreads();

    // phase B: PL / PR
    short8 wfL[2][4], wfR[2][4];
#pragma unroll
    for (int mt = 0; mt < 2; ++mt)
#pragma unroll
        for (int kt = 0; kt < 4; ++kt) {
            int row = w * 32 + mt * 16 + lr;
            int k   = kt * 32 + lg * 8;
            wfL[mt][kt] = load_wfrag(ow1, row, 256, k);
            wfR[mt][kt] = load_wfrag(ow1, row, 256, 128 + k);
        }
    f32x4 aL[2][4], aR[2][4];
#pragma unroll
    for (int mt = 0; mt < 2; ++mt)
#pragma unroll
        for (int nt = 0; nt < 4; ++nt) { aL[mt][nt] = (f32x4)0.0f; aR[mt][nt] = (f32x4)0.0f; }
#pragma unroll
    for (int kt = 0; kt < 4; ++kt) {
        short8 bf[4];
#pragma unroll
        for (int nt = 0; nt < 4; ++nt) {
            int e = nt * 16 + lr;
            int scol = (kt * 32 + lg * 8) ^ ((e & 7) << 3);
            bf[nt] = *(const short8*)&feat2[e * 128 + scol];
        }
#pragma unroll
        for (int mt = 0; mt < 2; ++mt)
#pragma unroll
            for (int nt = 0; nt < 4; ++nt) {
                aL[mt][nt] = MFMA16(wfL[mt][kt], bf[nt], aL[mt][nt]);
                aR[mt][nt] = MFMA16(wfR[mt][kt], bf[nt], aR[mt][nt]);
            }
    }
#pragma unroll
    for (int mt = 0; mt < 2; ++mt)
#pragma unroll
        for (int nt = 0; nt < 4; ++nt) {
            int ng = base + nt * 16 + lr;
            if (ng < N_NODES) {
                int n0 = w * 32 + mt * 16 + lg * 4;
                short4v oL, oR;
#pragma unroll
                for (int r = 0; r < 4; ++r) { oL[r] = f2bf(aL[mt][nt][r]); oR[r] = f2bf(aR[mt][nt][r]); }
                *(short4v*)&plb[(size_t)ng * 128 + n0] = oL;
                *(short4v*)&prb[(size_t)ng * 128 + n0] = oR;
            }
        }
}

__global__ __launch_bounds__(256) void k_ycopy(
    const int* __restrict__ y, float* __restrict__ out)
{
    int e = blockIdx.x * blockDim.x + threadIdx.x;
    if (e < N_EDGES) out[(size_t)N_EDGES * N_REL + e] = (float)y[e];
}

// ---------------- edge MLP v3: original order, prefetch, coalesced out ------
__global__ __launch_bounds__(256, 4) void k_edge3(
    const short* __restrict__ plb, const short* __restrict__ prb,
    const int* __restrict__ src, const int* __restrict__ dst,
    const float* __restrict__ ob1,
    const float* __restrict__ ow2, const float* __restrict__ ob2,
    const float* __restrict__ ow3, const float* __restrict__ ob3,
    const float* __restrict__ ow4, const float* __restrict__ ob4,
    const float* __restrict__ rw1, const float* __restrict__ rb1,
    const float* __restrict__ rw2, const float* __restrict__ rb2,
    const float* __restrict__ rw3, const float* __restrict__ rb3,
    float* __restrict__ out)
{
    __shared__ short a1s[64 * 128];    // 16KB; tail T aliases
    __shared__ short actB[64 * 96];    // act2 | act3
    __shared__ float sw[662];

    short* act2  = actB;
    short* act3  = actB + 64 * 64;
    float* tailf = (float*)a1s;

    const int t    = threadIdx.x;
    const int w    = t >> 6;
    const int lane = t & 63;
    const int lr   = lane & 15;
    const int lg   = lane >> 4;

    if (t < 128) sw[t]       = ob1[t];
    if (t < 64)  sw[128 + t] = ob2[t];
    if (t < 32)  sw[192 + t] = ob3[t];
    if (t < 16)  sw[224 + t] = ob4[t];
    if (t < 8)   sw[240 + t] = rb1[t];
    if (t < 4)   sw[248 + t] = rb2[t];
    if (t < 50)  sw[252 + t] = rb3[t];
    if (t < 128) sw[302 + t] = rw1[t];
    if (t < 32)  sw[430 + t] = rw2[t];
    if (t < 200) sw[462 + t] = rw3[t];

    short8 w2f[4];
#pragma unroll
    for (int kt = 0; kt < 4; ++kt)
        w2f[kt] = load_wfrag(ow2, w * 16 + lr, 128, kt * 32 + lg * 8);

    short8 w3f[2][2];
#pragma unroll
    for (int mt = 0; mt < 2; ++mt)
#pragma unroll
        for (int kt = 0; kt < 2; ++kt)
            w3f[mt][kt] = load_wfrag(ow3, mt * 16 + lr, 64, kt * 32 + lg * 8);

    short8 w4f = load_wfrag(ow4, lr, 32, lg * 8);

    __syncthreads();   // sw ready

    const int e = t >> 2, p = t & 3;
    short8 vl0, vl1, vl2, vl3, vr0, vr1, vr2, vr3;

#define LOADTILE(TI)                                                        \
    {                                                                       \
        int eg  = (TI) * 64 + e;                                            \
        int egc = eg < N_EDGES ? eg : N_EDGES - 1;                          \
        int sn = src[egc], dn = dst[egc];                                   \
        const short8* plp = (const short8*)(plb + (size_t)sn * 128 + p * 32); \
        const short8* prp = (const short8*)(prb + (size_t)dn * 128 + p * 32); \
        vl0 = plp[0]; vl1 = plp[1]; vl2 = plp[2]; vl3 = plp[3];             \
        vr0 = prp[0]; vr1 = prp[1]; vr2 = prp[2]; vr3 = prp[3];             \
    }

    LOADTILE(blockIdx.x)

    for (int tile = blockIdx.x; tile < NTILES; tile += EBLOCKS) {
        const int base = tile * 64;

        // ---- stage a1 = relu(PL[src] + PR[dst] + ob1), bf16, swizzled ----
        {
            short8 VL[4] = {vl0, vl1, vl2, vl3};
            short8 VR[4] = {vr0, vr1, vr2, vr3};
#pragma unroll
            for (int j = 0; j < 4; ++j) {
                short8 s;
#pragma unroll
                for (int i = 0; i < 8; ++i) {
                    float v = bf2f(VL[j][i]) + bf2f(VR[j][i]) + sw[p * 32 + j * 8 + i];
                    s[i] = f2bf(v > 0.0f ? v : 0.0f);
                }
                int scol = (p * 32 + j * 8) ^ ((e & 7) << 3);
                *(short8*)&a1s[e * 128 + scol] = s;
            }
        }
        __syncthreads();

        // ---- prefetch next tile (flies during L2 + tail) ----
        if (tile + EBLOCKS < NTILES) LOADTILE(tile + EBLOCKS)

        // ---- L2: 128 -> 64, relu ----
        {
            f32x4 acc[4];
            f32x4 bia;
#pragma unroll
            for (int r = 0; r < 4; ++r) bia[r] = sw[128 + w * 16 + lg * 4 + r];
#pragma unroll
            for (int nt = 0; nt < 4; ++nt) acc[nt] = bia;
#pragma unroll
            for (int kt = 0; kt < 4; ++kt) {
#pragma unroll
                for (int nt = 0; nt < 4; ++nt) {
                    int en = nt * 16 + lr;
                    int scol = (kt * 32 + lg * 8) ^ ((en & 7) << 3);
                    short8 bf = *(const short8*)&a1s[en * 128 + scol];
                    acc[nt] = MFMA16(w2f[kt], bf, acc[nt]);
                }
            }
#pragma unroll
            for (int nt = 0; nt < 4; ++nt) {
                int en = nt * 16 + lr;
                int n0 = w * 16 + lg * 4;
                short4v s;
#pragma unroll
                for (int r = 0; r < 4; ++r) {
                    float v = acc[nt][r];
                    s[r] = f2bf(v > 0.0f ? v : 0.0f);
                }
                *(short4v*)&act2[en * 64 + (n0 ^ ((en & 7) << 3))] = s;
            }
        }
        __syncthreads();   // act2 ready; a1s dead -> tail T may alias

        // ---- wave-local tail ----
        {
            const int e3 = w * 16 + lr;
            float* T = tailf + w * 512;

            f32x4 acc[2];
#pragma unroll
            for (int mt = 0; mt < 2; ++mt)
#pragma unroll
                for (int r = 0; r < 4; ++r) acc[mt][r] = sw[192 + mt * 16 + lg * 4 + r];
#pragma unroll
            for (int kt = 0; kt < 2; ++kt) {
                int scol = (kt * 32 + lg * 8) ^ ((e3 & 7) << 3);
                short8 bf = *(const short8*)&act2[e3 * 64 + scol];
#pragma unroll
                for (int mt = 0; mt < 2; ++mt)
                    acc[mt] = MFMA16(w3f[mt][kt], bf, acc[mt]);
            }
#pragma unroll
            for (int mt = 0; mt < 2; ++mt) {
                short4v s;
#pragma unroll
                for (int r = 0; r < 4; ++r) {
                    float v = acc[mt][r];
                    s[r] = f2bf(v > 0.0f ? v : 0.0f);
                }
                *(short4v*)&act3[e3 * 32 + mt * 16 + lg * 4] = s;
            }
            __builtin_amdgcn_wave_barrier();

            {
                short8 bf = *(const short8*)&act3[e3 * 32 + lg * 8];
                f32x4 a4;
#pragma unroll
                for (int r = 0; r < 4; ++r) a4[r] = sw[224 + lg * 4 + r];
                a4 = MFMA16(w4f, bf, a4);
#pragma unroll
                for (int r = 0; r < 4; ++r) T[lr * 17 + lg * 4 + r] = a4[r];
            }
            __builtin_amdgcn_wave_barrier();

            {
                float af[16];
#pragma unroll
                for (int f = 0; f < 16; ++f) af[f] = T[lr * 17 + f];
#pragma unroll
                for (int oo = 0; oo < 2; ++oo) {
                    int o = lg * 2 + oo;
                    float v = sw[240 + o];
#pragma unroll
                    for (int f = 0; f < 16; ++f) v += af[f] * sw[302 + o * 16 + f];
                    T[272 + lr * 9 + o] = v > 0.0f ? v : 0.0f;
                }
            }
            __builtin_amdgcn_wave_barrier();

            {
                float v = sw[248 + lg];
#pragma unroll
                for (int f = 0; f < 8; ++f) v += T[272 + lr * 9 + f] * sw[430 + lg * 8 + f];
                T[416 + lr * 5 + lg] = v > 0.0f ? v : 0.0f;
            }
            __builtin_amdgcn_wave_barrier();

            // rf3: 4 -> 50, COALESCED (original edge order)
            size_t obase = (size_t)(base + w * 16) * N_REL;
#pragma unroll
            for (int k2 = 0; k2 < 13; ++k2) {
                int idx = k2 * 64 + lane;
                if (idx < 16 * N_REL) {
                    int el = idx / N_REL;
                    int o  = idx - el * N_REL;
                    if (base + w * 16 + el < N_EDGES) {
                        float v = sw[252 + o];
#pragma unroll
                        for (int f = 0; f < 4; ++f) v += T[416 + el * 5 + f] * sw[462 + o * 4 + f];
                        out[obase + idx] = v;
                    }
                }
            }
        }
        __syncthreads();
    }
#undef LOADTILE
}

extern "C" void kernel_launch(void* const* d_in, const int* in_sizes, int n_in,
                              void* d_out, int out_size, void* d_ws, size_t ws_size,
                              hipStream_t stream) {
    const float* x    = (const float*)d_in[0];
    const int*   ei   = (const int*)d_in[1];
    const int*   src  = ei;
    const int*   dst  = ei + N_EDGES;
    const int*   y    = (const int*)d_in[2];
    const float* w1_l = (const float*)d_in[3];
    const float* b1   = (const float*)d_in[4];
    const float* w1_r = (const float*)d_in[5];
    const float* w2_l = (const float*)d_in[6];
    const float* b2   = (const float*)d_in[7];
    const float* w2_r = (const float*)d_in[8];
    const float* ow1  = (const float*)d_in[9];
    const float* ob1  = (const float*)d_in[10];
    const float* ow2  = (const float*)d_in[11];
    const float* ob2  = (const float*)d_in[12];
    const float* ow3  = (const float*)d_in[13];
    const float* ob3  = (const float*)d_in[14];
    const float* ow4  = (const float*)d_in[15];
    const float* ob4  = (const float*)d_in[16];
    const float* rw1  = (const float*)d_in[17];
    const float* rb1  = (const float*)d_in[18];
    const float* rw2  = (const float*)d_in[19];
    const float* rb2  = (const float*)d_in[20];
    const float* rw3  = (const float*)d_in[21];
    const float* rb3  = (const float*)d_in[22];

    float* ws     = (float*)d_ws;
    int*   cnt_i  = (int*)(ws + CNTI_OFF);
    int*   starts = (int*)(ws + STARTS_OFF);
    int*   cursor = (int*)(ws + CURSOR_OFF);
    int*   srcb   = (int*)(ws + SRCB_OFF);
    float* s1     = ws + S1_OFF;
    float* s2     = ws + S2_OFF;
    short* h1b    = (short*)(ws + H1_OFF);
    short* plb    = (short*)(ws + H2_OFF);
    short* prb    = (short*)(ws + S2_OFF);   // overwrites s2 in k_sage2p (safe)
    float* out    = (float*)d_out;

    hipMemsetAsync(cnt_i, 0, N_NODES * sizeof(int), stream);

    k_hist  <<<(N_EDGES + 255) / 256, 256, 0, stream>>>(dst, cnt_i);
    k_scan  <<<1, 1024, 0, stream>>>(cnt_i, starts, cursor);
    k_bucket<<<(N_EDGES + 255) / 256, 256, 0, stream>>>(src, dst, cursor, srcb);

    k_agg1<<<(N_NODES * 16 + 255) / 256, 256, 0, stream>>>(x, srcb, starts, cnt_i, s1);
    k_sage1_mfma<<<NODE_TILES, 256, 0, stream>>>(x, s1, cnt_i, w1_l, b1, w1_r, h1b);

    k_agg2<<<(N_NODES * 64 + 255) / 256, 256, 0, stream>>>(h1b, srcb, starts, cnt_i, s2);
    k_sage2p<<<NODE_TILES, 256, 0, stream>>>(h1b, s2, cnt_i, w2_l, b2, w2_r, ow1, plb, prb);

    k_ycopy<<<(N_EDGES + 255) / 256, 256, 0, stream>>>(y, out);

    k_edge3<<<EBLOCKS, 256, 0, stream>>>(
        plb, prb, src, dst,
        ob1, ow2, ob2, ow3, ob3, ow4, ob4,
        rw1, rb1, rw2, rb2, rw3, rb3, out);
}

// Round 8
// 411.023 us; speedup vs baseline: 1.9630x; 1.0862x over previous
//
#include <hip/hip_runtime.h>
#include <hip/hip_bf16.h>

#define N_NODES 50000
#define N_EDGES 500000
#define N_REL   50
#define NTILES  ((N_EDGES + 63) / 64)   // 7813
#define EBLOCKS 1024
#define NODE_TILES ((N_NODES + 63) / 64)  // 782

// workspace layout (float-sized slots)
#define CNTI_OFF   0                          // int[50000]  (memset to 0)
#define STARTS_OFF (CNTI_OFF + N_NODES)
#define CURSOR_OFF (STARTS_OFF + N_NODES)
#define SRCB_OFF   (CURSOR_OFF + N_NODES)     // int[500000] src grouped by dst
#define PRB_OFF    (SRCB_OFF + N_EDGES)       // short[50000*128] (bf16) = 3.2M floats
#define H1_OFF     (PRB_OFF + N_NODES*32)     // short[50000*64]  (bf16)
#define PLB_OFF    (H1_OFF + N_NODES*32)      // short[50000*128] (bf16)
// end = PLB_OFF + N_NODES*32 = 8.65M floats = 34.6 MB

typedef short short8  __attribute__((ext_vector_type(8)));
typedef short short4v __attribute__((ext_vector_type(4)));
typedef float f32x4   __attribute__((ext_vector_type(4)));
typedef float f4      __attribute__((ext_vector_type(4)));

#define MFMA16(a,b,c) __builtin_amdgcn_mfma_f32_16x16x32_bf16((a),(b),(c),0,0,0)

__device__ __forceinline__ short f2bf(float x) {
    unsigned u = __float_as_uint(x);
    unsigned r = (u + 0x7fffu + ((u >> 16) & 1u)) >> 16;   // RNE
    return (short)r;
}
__device__ __forceinline__ float bf2f(short s) {
    return __uint_as_float(((unsigned)(unsigned short)s) << 16);
}

__device__ __forceinline__ short8 load_wfrag(const float* __restrict__ W, int row, int K, int k) {
    const f4* p = (const f4*)(W + (size_t)row * K + k);
    f4 a = p[0], b = p[1];
    short8 r;
    r[0] = f2bf(a[0]); r[1] = f2bf(a[1]); r[2] = f2bf(a[2]); r[3] = f2bf(a[3]);
    r[4] = f2bf(b[0]); r[5] = f2bf(b[1]); r[6] = f2bf(b[2]); r[7] = f2bf(b[3]);
    return r;
}

// ---------------- CSR build ----------------

// hist of dst + y->out copy (fused: same grid shape)
__global__ __launch_bounds__(256) void k_histy(
    const int* __restrict__ dst, int* __restrict__ cnt_i,
    const int* __restrict__ y, float* __restrict__ out)
{
    int e = blockIdx.x * blockDim.x + threadIdx.x;
    if (e < N_EDGES) {
        atomicAdd(&cnt_i[dst[e]], 1);
        out[(size_t)N_EDGES * N_REL + e] = (float)y[e];
    }
}

__global__ __launch_bounds__(1024) void k_scan(
    const int* __restrict__ cnt_i, int* __restrict__ starts, int* __restrict__ cursor)
{
    __shared__ int part[1024];
    const int i  = threadIdx.x;
    const int lo = i * 49;
    const int hi = min(N_NODES, lo + 49);
    int s = 0;
    for (int j = lo; j < hi; ++j) s += cnt_i[j];
    part[i] = s;
    __syncthreads();
    for (int d = 1; d < 1024; d <<= 1) {
        int v = (i >= d) ? part[i - d] : 0;
        __syncthreads();
        part[i] += v;
        __syncthreads();
    }
    int off = (i == 0) ? 0 : part[i - 1];
    for (int j = lo; j < hi; ++j) {
        starts[j] = off;
        cursor[j] = off;
        off += cnt_i[j];
    }
}

__global__ __launch_bounds__(256) void k_bucket(
    const int* __restrict__ src, const int* __restrict__ dst,
    int* __restrict__ cursor, int* __restrict__ srcb)
{
    int e = blockIdx.x * blockDim.x + threadIdx.x;
    if (e < N_EDGES) {
        int pos = atomicAdd(&cursor[dst[e]], 1);
        srcb[pos] = src[e];
    }
}

// ---------------- SAGE1 with fused in-edge gather ----------------
// staging thread (e, q): q<2 -> mean feats q*8..+8 via CSR gather-sum over x;
// q>=2 -> self x feats. K layout: [0,16)=mean (w1_l), [16,32)=x (w1_r).
__global__ __launch_bounds__(256) void k_sage1g(
    const float* __restrict__ x, const int* __restrict__ srcb,
    const int* __restrict__ starts, const int* __restrict__ cnt_i,
    const float* __restrict__ w1_l, const float* __restrict__ b1,
    const float* __restrict__ w1_r, short* __restrict__ h1b)
{
    __shared__ short feat[64 * 40];

    const int t    = threadIdx.x;
    const int w    = t >> 6;
    const int lane = t & 63;
    const int lr   = lane & 15;
    const int lg   = lane >> 4;
    const int base = blockIdx.x * 64;

    short8 w1f;
    if (lg < 2) w1f = load_wfrag(w1_l, w * 16 + lr, 16, lg * 8);
    else        w1f = load_wfrag(w1_r, w * 16 + lr, 16, (lg - 2) * 8);

    {
        int e  = t >> 2, q = t & 3;
        int ng = base + e;
        short8 v = (short8)0;
        if (ng < N_NODES) {
            if (q < 2) {
                int st = starts[ng], c = cnt_i[ng];
                float acc[8] = {0, 0, 0, 0, 0, 0, 0, 0};
                for (int i = 0; i < c; ++i) {
                    const float* xp = x + (size_t)srcb[st + i] * 16 + q * 8;
                    f4 a = *(const f4*)xp;
                    f4 b = *(const f4*)(xp + 4);
#pragma unroll
                    for (int j = 0; j < 4; ++j) { acc[j] += a[j]; acc[4 + j] += b[j]; }
                }
                float inv = 1.0f / (float)(c > 0 ? c : 1);
#pragma unroll
                for (int j = 0; j < 8; ++j) v[j] = f2bf(acc[j] * inv);
            } else {
                f4 a = *(const f4*)(x + (size_t)ng * 16 + (q - 2) * 8);
                f4 b = *(const f4*)(x + (size_t)ng * 16 + (q - 2) * 8 + 4);
#pragma unroll
                for (int j = 0; j < 4; ++j) { v[j] = f2bf(a[j]); v[4 + j] = f2bf(b[j]); }
            }
        }
        *(short8*)&feat[e * 40 + q * 8] = v;
    }
    __syncthreads();

    f32x4 acc[4];
    f4 bia = *(const f4*)&b1[w * 16 + lg * 4];
#pragma unroll
    for (int nt = 0; nt < 4; ++nt) {
        acc[nt][0] = bia[0]; acc[nt][1] = bia[1]; acc[nt][2] = bia[2]; acc[nt][3] = bia[3];
    }
#pragma unroll
    for (int nt = 0; nt < 4; ++nt) {
        int e = nt * 16 + lr;
        short8 bf = *(const short8*)&feat[e * 40 + lg * 8];
        acc[nt] = MFMA16(w1f, bf, acc[nt]);
    }
#pragma unroll
    for (int nt = 0; nt < 4; ++nt) {
        int ng = base + nt * 16 + lr;
        if (ng < N_NODES) {
            short4v o;
#pragma unroll
            for (int r = 0; r < 4; ++r) { float v = acc[nt][r]; o[r] = f2bf(v > 0.0f ? v : 0.0f); }
            *(short4v*)&h1b[(size_t)ng * 64 + w * 16 + lg * 4] = o;
        }
    }
}

// ---------------- SAGE2 + proj, with fused in-edge gather ----------------
// staging thread (e, q): q<2 -> self h1 feats q*32..+32 (K slots [0,64), w2_r);
// q>=2 -> mean via CSR gather-sum over h1b, feats (q-2)*32..+32 (K slots
// [64,128), w2_l). Then phase A (h2 tile in LDS) and phase B (PL/PR GEMMs).
__global__ __launch_bounds__(256) void k_sage2g(
    const short* __restrict__ h1b, const int* __restrict__ srcb,
    const int* __restrict__ starts, const int* __restrict__ cnt_i,
    const float* __restrict__ w2_l, const float* __restrict__ b2,
    const float* __restrict__ w2_r, const float* __restrict__ ow1,
    short* __restrict__ plb, short* __restrict__ prb)
{
    __shared__ short feat[64 * 128];
    __shared__ short feat2[64 * 128];

    const int t    = threadIdx.x;
    const int w    = t >> 6;
    const int lane = t & 63;
    const int lr   = lane & 15;
    const int lg   = lane >> 4;
    const int base = blockIdx.x * 64;

    short8 wf[2][4];
#pragma unroll
    for (int mt = 0; mt < 2; ++mt)
#pragma unroll
        for (int kt = 0; kt < 4; ++kt) {
            int row = w * 32 + mt * 16 + lr;
            int k   = kt * 32 + lg * 8;
            wf[mt][kt] = (k < 64) ? load_wfrag(w2_r, row, 64, k)
                                  : load_wfrag(w2_l, row, 64, k - 64);
        }

    {
        int e  = t >> 2, q = t & 3;
        int ng = base + e;
        if (q < 2) {
            const short* hp = (ng < N_NODES) ? (h1b + (size_t)ng * 64 + q * 32) : nullptr;
#pragma unroll
            for (int j = 0; j < 4; ++j) {
                short8 v = hp ? *(const short8*)(hp + j * 8) : (short8)0;
                int scol = (q * 32 + j * 8) ^ ((e & 7) << 3);
                *(short8*)&feat[e * 128 + scol] = v;
            }
        } else {
            float acc[32];
#pragma unroll
            for (int j = 0; j < 32; ++j) acc[j] = 0.0f;
            int c = 0;
            if (ng < N_NODES) {
                int st = starts[ng];
                c = cnt_i[ng];
                for (int i = 0; i < c; ++i) {
                    const short8* hp = (const short8*)(h1b + (size_t)srcb[st + i] * 64 + (q - 2) * 32);
                    short8 a0 = hp[0], a1 = hp[1], a2 = hp[2], a3 = hp[3];
#pragma unroll
                    for (int j = 0; j < 8; ++j) {
                        acc[j]      += bf2f(a0[j]);
                        acc[8 + j]  += bf2f(a1[j]);
                        acc[16 + j] += bf2f(a2[j]);
                        acc[24 + j] += bf2f(a3[j]);
                    }
                }
            }
            float inv = 1.0f / (float)(c > 0 ? c : 1);
#pragma unroll
            for (int jj = 0; jj < 4; ++jj) {
                short8 v;
#pragma unroll
                for (int j = 0; j < 8; ++j) v[j] = f2bf(acc[jj * 8 + j] * inv);
                int scol = ((q - 2) * 32 + 64 + jj * 8) ^ ((e & 7) << 3);
                *(short8*)&feat[e * 128 + scol] = v;
            }
        }
    }
    __syncthreads();

    // phase A: h2 tile (bf16, swizzled, LDS only)
    {
        f32x4 acc[2][4];
#pragma unroll
        for (int mt = 0; mt < 2; ++mt) {
            f4 bia = *(const f4*)&b2[w * 32 + mt * 16 + lg * 4];
#pragma unroll
            for (int nt = 0; nt < 4; ++nt) {
                acc[mt][nt][0] = bia[0]; acc[mt][nt][1] = bia[1];
                acc[mt][nt][2] = bia[2]; acc[mt][nt][3] = bia[3];
            }
        }
#pragma unroll
        for (int kt = 0; kt < 4; ++kt) {
            short8 bf[4];
#pragma unroll
            for (int nt = 0; nt < 4; ++nt) {
                int e = nt * 16 + lr;
                int scol = (kt * 32 + lg * 8) ^ ((e & 7) << 3);
                bf[nt] = *(const short8*)&feat[e * 128 + scol];
            }
#pragma unroll
            for (int mt = 0; mt < 2; ++mt)
#pragma unroll
                for (int nt = 0; nt < 4; ++nt)
                    acc[mt][nt] = MFMA16(wf[mt][kt], bf[nt], acc[mt][nt]);
        }
#pragma unroll
        for (int mt = 0; mt < 2; ++mt)
#pragma unroll
            for (int nt = 0; nt < 4; ++nt) {
                int e  = nt * 16 + lr;
                int n0 = w * 32 + mt * 16 + lg * 4;
                short4v s;
#pragma unroll
                for (int r = 0; r < 4; ++r) {
                    float v = acc[mt][nt][r];
                    s[r] = f2bf(v > 0.0f ? v : 0.0f);
                }
                *(short4v*)&feat2[e * 128 + (n0 ^ ((e & 7) << 3))] = s;
            }
    }
    __syncthreads();

    // phase B: PL / PR projections
    short8 wfL[2][4], wfR[2][4];
#pragma unroll
    for (int mt = 0; mt < 2; ++mt)
#pragma unroll
        for (int kt = 0; kt < 4; ++kt) {
            int row = w * 32 + mt * 16 + lr;
            int k   = kt * 32 + lg * 8;
            wfL[mt][kt] = load_wfrag(ow1, row, 256, k);
            wfR[mt][kt] = load_wfrag(ow1, row, 256, 128 + k);
        }
    f32x4 aL[2][4], aR[2][4];
#pragma unroll
    for (int mt = 0; mt < 2; ++mt)
#pragma unroll
        for (int nt = 0; nt < 4; ++nt) { aL[mt][nt] = (f32x4)0.0f; aR[mt][nt] = (f32x4)0.0f; }
#pragma unroll
    for (int kt = 0; kt < 4; ++kt) {
        short8 bf[4];
#pragma unroll
        for (int nt = 0; nt < 4; ++nt) {
            int e = nt * 16 + lr;
            int scol = (kt * 32 + lg * 8) ^ ((e & 7) << 3);
            bf[nt] = *(const short8*)&feat2[e * 128 + scol];
        }
#pragma unroll
        for (int mt = 0; mt < 2; ++mt)
#pragma unroll
            for (int nt = 0; nt < 4; ++nt) {
                aL[mt][nt] = MFMA16(wfL[mt][kt], bf[nt], aL[mt][nt]);
                aR[mt][nt] = MFMA16(wfR[mt][kt], bf[nt], aR[mt][nt]);
            }
    }
#pragma unroll
    for (int mt = 0; mt < 2; ++mt)
#pragma unroll
        for (int nt = 0; nt < 4; ++nt) {
            int ng = base + nt * 16 + lr;
            if (ng < N_NODES) {
                int n0 = w * 32 + mt * 16 + lg * 4;
                short4v oL, oR;
#pragma unroll
                for (int r = 0; r < 4; ++r) { oL[r] = f2bf(aL[mt][nt][r]); oR[r] = f2bf(aR[mt][nt][r]); }
                *(short4v*)&plb[(size_t)ng * 128 + n0] = oL;
                *(short4v*)&prb[(size_t)ng * 128 + n0] = oR;
            }
        }
}

// ---------------- edge MLP v3: original order, prefetch, coalesced out ------
__global__ __launch_bounds__(256, 4) void k_edge3(
    const short* __restrict__ plb, const short* __restrict__ prb,
    const int* __restrict__ src, const int* __restrict__ dst,
    const float* __restrict__ ob1,
    const float* __restrict__ ow2, const float* __restrict__ ob2,
    const float* __restrict__ ow3, const float* __restrict__ ob3,
    const float* __restrict__ ow4, const float* __restrict__ ob4,
    const float* __restrict__ rw1, const float* __restrict__ rb1,
    const float* __restrict__ rw2, const float* __restrict__ rb2,
    const float* __restrict__ rw3, const float* __restrict__ rb3,
    float* __restrict__ out)
{
    __shared__ short a1s[64 * 128];    // 16KB; tail T aliases
    __shared__ short actB[64 * 96];    // act2 | act3
    __shared__ float sw[662];

    short* act2  = actB;
    short* act3  = actB + 64 * 64;
    float* tailf = (float*)a1s;

    const int t    = threadIdx.x;
    const int w    = t >> 6;
    const int lane = t & 63;
    const int lr   = lane & 15;
    const int lg   = lane >> 4;

    if (t < 128) sw[t]       = ob1[t];
    if (t < 64)  sw[128 + t] = ob2[t];
    if (t < 32)  sw[192 + t] = ob3[t];
    if (t < 16)  sw[224 + t] = ob4[t];
    if (t < 8)   sw[240 + t] = rb1[t];
    if (t < 4)   sw[248 + t] = rb2[t];
    if (t < 50)  sw[252 + t] = rb3[t];
    if (t < 128) sw[302 + t] = rw1[t];
    if (t < 32)  sw[430 + t] = rw2[t];
    if (t < 200) sw[462 + t] = rw3[t];

    short8 w2f[4];
#pragma unroll
    for (int kt = 0; kt < 4; ++kt)
        w2f[kt] = load_wfrag(ow2, w * 16 + lr, 128, kt * 32 + lg * 8);

    short8 w3f[2][2];
#pragma unroll
    for (int mt = 0; mt < 2; ++mt)
#pragma unroll
        for (int kt = 0; kt < 2; ++kt)
            w3f[mt][kt] = load_wfrag(ow3, mt * 16 + lr, 64, kt * 32 + lg * 8);

    short8 w4f = load_wfrag(ow4, lr, 32, lg * 8);

    __syncthreads();   // sw ready

    const int e = t >> 2, p = t & 3;
    short8 vl0, vl1, vl2, vl3, vr0, vr1, vr2, vr3;

#define LOADTILE(TI)                                                        \
    {                                                                       \
        int eg  = (TI) * 64 + e;                                            \
        int egc = eg < N_EDGES ? eg : N_EDGES - 1;                          \
        int sn = src[egc], dn = dst[egc];                                   \
        const short8* plp = (const short8*)(plb + (size_t)sn * 128 + p * 32); \
        const short8* prp = (const short8*)(prb + (size_t)dn * 128 + p * 32); \
        vl0 = plp[0]; vl1 = plp[1]; vl2 = plp[2]; vl3 = plp[3];             \
        vr0 = prp[0]; vr1 = prp[1]; vr2 = prp[2]; vr3 = prp[3];             \
    }

    LOADTILE(blockIdx.x)

    for (int tile = blockIdx.x; tile < NTILES; tile += EBLOCKS) {
        const int base = tile * 64;

        // ---- stage a1 = relu(PL[src] + PR[dst] + ob1), bf16, swizzled ----
        {
            short8 VL[4] = {vl0, vl1, vl2, vl3};
            short8 VR[4] = {vr0, vr1, vr2, vr3};
#pragma unroll
            for (int j = 0; j < 4; ++j) {
                short8 s;
#pragma unroll
                for (int i = 0; i < 8; ++i) {
                    float v = bf2f(VL[j][i]) + bf2f(VR[j][i]) + sw[p * 32 + j * 8 + i];
                    s[i] = f2bf(v > 0.0f ? v : 0.0f);
                }
                int scol = (p * 32 + j * 8) ^ ((e & 7) << 3);
                *(short8*)&a1s[e * 128 + scol] = s;
            }
        }
        __syncthreads();

        // ---- prefetch next tile (flies during L2 + tail) ----
        if (tile + EBLOCKS < NTILES) LOADTILE(tile + EBLOCKS)

        // ---- L2: 128 -> 64, relu ----
        {
            f32x4 acc[4];
            f32x4 bia;
#pragma unroll
            for (int r = 0; r < 4; ++r) bia[r] = sw[128 + w * 16 + lg * 4 + r];
#pragma unroll
            for (int nt = 0; nt < 4; ++nt) acc[nt] = bia;
#pragma unroll
            for (int kt = 0; kt < 4; ++kt) {
#pragma unroll
                for (int nt = 0; nt < 4; ++nt) {
                    int en = nt * 16 + lr;
                    int scol = (kt * 32 + lg * 8) ^ ((en & 7) << 3);
                    short8 bf = *(const short8*)&a1s[en * 128 + scol];
                    acc[nt] = MFMA16(w2f[kt], bf, acc[nt]);
                }
            }
#pragma unroll
            for (int nt = 0; nt < 4; ++nt) {
                int en = nt * 16 + lr;
                int n0 = w * 16 + lg * 4;
                short4v s;
#pragma unroll
                for (int r = 0; r < 4; ++r) {
                    float v = acc[nt][r];
                    s[r] = f2bf(v > 0.0f ? v : 0.0f);
                }
                *(short4v*)&act2[en * 64 + (n0 ^ ((en & 7) << 3))] = s;
            }
        }
        __syncthreads();   // act2 ready; a1s dead -> tail T may alias

        // ---- wave-local tail ----
        {
            const int e3 = w * 16 + lr;
            float* T = tailf + w * 512;

            f32x4 acc[2];
#pragma unroll
            for (int mt = 0; mt < 2; ++mt)
#pragma unroll
                for (int r = 0; r < 4; ++r) acc[mt][r] = sw[192 + mt * 16 + lg * 4 + r];
#pragma unroll
            for (int kt = 0; kt < 2; ++kt) {
                int scol = (kt * 32 + lg * 8) ^ ((e3 & 7) << 3);
                short8 bf = *(const short8*)&act2[e3 * 64 + scol];
#pragma unroll
                for (int mt = 0; mt < 2; ++mt)
                    acc[mt] = MFMA16(w3f[mt][kt], bf, acc[mt]);
            }
#pragma unroll
            for (int mt = 0; mt < 2; ++mt) {
                short4v s;
#pragma unroll
                for (int r = 0; r < 4; ++r) {
                    float v = acc[mt][r];
                    s[r] = f2bf(v > 0.0f ? v : 0.0f);
                }
                *(short4v*)&act3[e3 * 32 + mt * 16 + lg * 4] = s;
            }
            __builtin_amdgcn_wave_barrier();

            {
                short8 bf = *(const short8*)&act3[e3 * 32 + lg * 8];
                f32x4 a4;
#pragma unroll
                for (int r = 0; r < 4; ++r) a4[r] = sw[224 + lg * 4 + r];
                a4 = MFMA16(w4f, bf, a4);
#pragma unroll
                for (int r = 0; r < 4; ++r) T[lr * 17 + lg * 4 + r] = a4[r];
            }
            __builtin_amdgcn_wave_barrier();

            {
                float af[16];
#pragma unroll
                for (int f = 0; f < 16; ++f) af[f] = T[lr * 17 + f];
#pragma unroll
                for (int oo = 0; oo < 2; ++oo) {
                    int o = lg * 2 + oo;
                    float v = sw[240 + o];
#pragma unroll
                    for (int f = 0; f < 16; ++f) v += af[f] * sw[302 + o * 16 + f];
                    T[272 + lr * 9 + o] = v > 0.0f ? v : 0.0f;
                }
            }
            __builtin_amdgcn_wave_barrier();

            {
                float v = sw[248 + lg];
#pragma unroll
                for (int f = 0; f < 8; ++f) v += T[272 + lr * 9 + f] * sw[430 + lg * 8 + f];
                T[416 + lr * 5 + lg] = v > 0.0f ? v : 0.0f;
            }
            __builtin_amdgcn_wave_barrier();

            // rf3: 4 -> 50, COALESCED (original edge order)
            size_t obase = (size_t)(base + w * 16) * N_REL;
#pragma unroll
            for (int k2 = 0; k2 < 13; ++k2) {
                int idx = k2 * 64 + lane;
                if (idx < 16 * N_REL) {
                    int el = idx / N_REL;
                    int o  = idx - el * N_REL;
                    if (base + w * 16 + el < N_EDGES) {
                        float v = sw[252 + o];
#pragma unroll
                        for (int f = 0; f < 4; ++f) v += T[416 + el * 5 + f] * sw[462 + o * 4 + f];
                        out[obase + idx] = v;
                    }
                }
            }
        }
        __syncthreads();
    }
#undef LOADTILE
}

extern "C" void kernel_launch(void* const* d_in, const int* in_sizes, int n_in,
                              void* d_out, int out_size, void* d_ws, size_t ws_size,
                              hipStream_t stream) {
    const float* x    = (const float*)d_in[0];
    const int*   ei   = (const int*)d_in[1];
    const int*   src  = ei;
    const int*   dst  = ei + N_EDGES;
    const int*   y    = (const int*)d_in[2];
    const float* w1_l = (const float*)d_in[3];
    const float* b1   = (const float*)d_in[4];
    const float* w1_r = (const float*)d_in[5];
    const float* w2_l = (const float*)d_in[6];
    const float* b2   = (const float*)d_in[7];
    const float* w2_r = (const float*)d_in[8];
    const float* ow1  = (const float*)d_in[9];
    const float* ob1  = (const float*)d_in[10];
    const float* ow2  = (const float*)d_in[11];
    const float* ob2  = (const float*)d_in[12];
    const float* ow3  = (const float*)d_in[13];
    const float* ob3  = (const float*)d_in[14];
    const float* ow4  = (const float*)d_in[15];
    const float* ob4  = (const float*)d_in[16];
    const float* rw1  = (const float*)d_in[17];
    const float* rb1  = (const float*)d_in[18];
    const float* rw2  = (const float*)d_in[19];
    const float* rb2  = (const float*)d_in[20];
    const float* rw3  = (const float*)d_in[21];
    const float* rb3  = (const float*)d_in[22];

    float* ws     = (float*)d_ws;
    int*   cnt_i  = (int*)(ws + CNTI_OFF);
    int*   starts = (int*)(ws + STARTS_OFF);
    int*   cursor = (int*)(ws + CURSOR_OFF);
    int*   srcb   = (int*)(ws + SRCB_OFF);
    short* prb    = (short*)(ws + PRB_OFF);
    short* h1b    = (short*)(ws + H1_OFF);
    short* plb    = (short*)(ws + PLB_OFF);
    float* out    = (float*)d_out;

    hipMemsetAsync(cnt_i, 0, N_NODES * sizeof(int), stream);

    k_histy <<<(N_EDGES + 255) / 256, 256, 0, stream>>>(dst, cnt_i, y, out);
    k_scan  <<<1, 1024, 0, stream>>>(cnt_i, starts, cursor);
    k_bucket<<<(N_EDGES + 255) / 256, 256, 0, stream>>>(src, dst, cursor, srcb);

    k_sage1g<<<NODE_TILES, 256, 0, stream>>>(x, srcb, starts, cnt_i, w1_l, b1, w1_r, h1b);
    k_sage2g<<<NODE_TILES, 256, 0, stream>>>(h1b, srcb, starts, cnt_i,
                                             w2_l, b2, w2_r, ow1, plb, prb);

    k_edge3<<<EBLOCKS, 256, 0, stream>>>(
        plb, prb, src, dst,
        ob1, ow2, ob2, ow3, ob3, ow4, ob4,
        rw1, rb1, rw2, rb2, rw3, rb3, out);
}